// Round 3
// baseline (18513.907 us; speedup 1.0000x reference)
//
#include <hip/hip_runtime.h>
#include <stdint.h>
#include <stddef.h>

#define TT   128
#define BB   1024
#define INN  75
#define HH   128
#define KXP  96
#define OUTN 256
#define DECN 9600
#define EPSB 1e-5f

typedef short v8s __attribute__((ext_vector_type(8)));   // 8 bf16 (4 VGPR) MFMA frag
typedef float v4f __attribute__((ext_vector_type(4)));   // 4 fp32 acc frag
typedef unsigned short ush;
typedef unsigned int   u32;
typedef unsigned long long u64;

// ---- static device workspace (fully rewritten every launch) ----
__device__ __align__(256) ush g_xpad[(size_t)TT * BB * KXP];   // x padded to K=96, [t][b][k] bf16
__device__ __align__(256) u64 g_G1[(size_t)TT * 32 * BB * 4];  // BN(x@Wih0)+b0, [t][g][row][16 bf16]
__device__ __align__(256) u64 g_h0s[(size_t)TT * BB * 32];     // h0 stream [t][row][128 bf16] as u64
__device__ __align__(256) u64 g_h1s[(size_t)TT * BB * 32];     // h1 stream
// weights [m][k] bf16, m permuted: origcol(m) = (m&3)*128 + (m>>4)*4 + ((m>>2)&3)
__device__ __align__(256) ush g_wtih0[512 * KXP];
__device__ __align__(256) ush g_wthh0[512 * HH];
__device__ __align__(256) ush g_wtih1[512 * HH];
__device__ __align__(256) ush g_wthh1[512 * HH];
__device__ __align__(256) ush g_fcwt[OUTN * HH];               // fc_w^T [col][k]
__device__ __align__(256) ush g_decwt[(size_t)DECN * OUTN];    // dec_w^T [col][k]
__device__ __align__(256) ush g_emb[BB * OUTN];                // fc output bf16

// ---- sync state: monotone u32 counters, each += TT per launch (replay-safe) ----
__device__ u32 g_F1[2][32][4];     // gate partials published, owner (L,g,q)
__device__ u32 g_F2[2][32][4];     // c partials published
__device__ u32 g_F3[4][32];        // h0[t] published by L0 (g,q)  [quarter-major]
__device__ u32 g_F4[4][32];        // h1[t] published by L1 (g,q)
__device__ u32 g_agg[4][4];        // [q][0]=h0-ready-for-L0, [1]=h0-ready-for-L1, [2]=h1-ready
// partial-stat mailboxes (no t index; generation-gated by F1/F2 chain — see proof in krec3)
__device__ __align__(256) float g_gp[2 * 32 * 4 * 64];   // [(L,g,q)][streamA 32f | streamB 32f]
__device__ __align__(256) float g_cp[2 * 32 * 4 * 16];   // [(L,g,q)][4 units x S,Q  (pad 16)]

// ---- helpers ----
__device__ __forceinline__ ush f2bf(float f) {
  u32 u = __float_as_uint(f);
  u32 r = (u + 0x7FFFu + ((u >> 16) & 1u)) >> 16;   // RNE
  return (ush)r;
}
__device__ __forceinline__ float bf2f(ush u) { return __uint_as_float(((u32)u) << 16); }
__device__ __forceinline__ float sigf(float x)  { return 1.f / (1.f + __expf(-x)); }
__device__ __forceinline__ float tanhf_(float x){ float e = __expf(2.f * x); return 1.f - 2.f / (e + 1.f); }
__device__ __forceinline__ v8s ld8(const ush* p) { return *reinterpret_cast<const v8s*>(p); }
__device__ __forceinline__ int origcol(int m) { return (m & 3) * 128 + (m >> 4) * 4 + ((m >> 2) & 3); }

__device__ __forceinline__ u32 aload(const u32* p) {
  return __hip_atomic_load(p, __ATOMIC_RELAXED, __HIP_MEMORY_SCOPE_AGENT);
}
__device__ __forceinline__ void astore(u32* p, u32 v) {
  __hip_atomic_store(p, v, __ATOMIC_RELEASE, __HIP_MEMORY_SCOPE_AGENT);
}
__device__ __forceinline__ void pollge(const u32* p, u32 tgt) {
  while (aload(p) < tgt) __builtin_amdgcn_s_sleep(2);
}

// ---- prep kernels (unchanged, verified) ----
__global__ void kpackx(const float* __restrict__ seq) {
  int idx = blockIdx.x * 256 + threadIdx.x;   // < TT*BB*KXP
  int kk = idx % KXP; int rest = idx / KXP;
  int b = rest % BB;  int t = rest / BB;
  float v = (kk < INN) ? seq[((size_t)b * TT + t) * INN + kk] : 0.f;
  g_xpad[idx] = f2bf(v);
}

__global__ void kpackw(const float* __restrict__ Wih0, const float* __restrict__ Whh0,
                       const float* __restrict__ Wih1, const float* __restrict__ Whh1,
                       const float* __restrict__ fcw,  const float* __restrict__ decw) {
  int idx = blockIdx.x * 256 + threadIdx.x;   // grid 10688
  if (idx < 49152) {                          // wtih0: [m][96]
    int m = idx / KXP, k = idx % KXP;
    g_wtih0[idx] = f2bf((k < INN) ? Wih0[k * 512 + origcol(m)] : 0.f);
  } else if (idx < 114688) {
    int j = idx - 49152; int m = j / HH, k = j % HH;
    g_wthh0[j] = f2bf(Whh0[k * 512 + origcol(m)]);
  } else if (idx < 180224) {
    int j = idx - 114688; int m = j / HH, k = j % HH;
    g_wtih1[j] = f2bf(Wih1[k * 512 + origcol(m)]);
  } else if (idx < 245760) {
    int j = idx - 180224; int m = j / HH, k = j % HH;
    g_wthh1[j] = f2bf(Whh1[k * 512 + origcol(m)]);
  } else if (idx < 278528) {                  // fcwt [c][128]
    int j = idx - 245760; int c = j / HH, k = j % HH;
    g_fcwt[j] = f2bf(fcw[k * OUTN + c]);
  } else {                                    // decwt [c][256], coalesced reads
    int j = idx - 278528; int n = j % DECN, k = j / DECN;
    g_decwt[(size_t)n * OUTN + k] = f2bf(decw[(size_t)k * DECN + n]);
  }
}

// G1[t][g][row][16] = BN_ih0(x_t @ Wih0) + b0 (folded), transposed-MFMA orientation.
__global__ __launch_bounds__(512) void kprep(const float* __restrict__ gih0,
                                             const float* __restrict__ bih0,
                                             const float* __restrict__ b0) {
  const int t = blockIdx.x >> 3, ct = blockIdx.x & 7;
  const int tid = threadIdx.x, wv = tid >> 6, l = tid & 63;
  const int lm = l & 15, lq = l >> 4;
  const int R0 = wv * 128;
  __shared__ float sred[8][64][2];
  __shared__ float scoef[64][2];

  v8s af[4][3];
#pragma unroll
  for (int tt = 0; tt < 4; ++tt)
#pragma unroll
    for (int ks = 0; ks < 3; ++ks)
      af[tt][ks] = ld8(&g_wtih0[(ct * 64 + tt * 16 + lm) * KXP + ks * 32 + lq * 8]);

  const v4f vz = {0.f, 0.f, 0.f, 0.f};
  v4f acc[8][4];
#pragma unroll
  for (int mt = 0; mt < 8; ++mt)
#pragma unroll
    for (int tt = 0; tt < 4; ++tt) acc[mt][tt] = vz;

#pragma unroll
  for (int mt = 0; mt < 8; ++mt) {
    const ush* xr = g_xpad + ((size_t)t * BB + R0 + mt * 16 + lm) * KXP + lq * 8;
    v8s bx0 = ld8(xr), bx1 = ld8(xr + 32), bx2 = ld8(xr + 64);
#pragma unroll
    for (int tt = 0; tt < 4; ++tt) {
      acc[mt][tt] = __builtin_amdgcn_mfma_f32_16x16x32_bf16(af[tt][0], bx0, acc[mt][tt], 0, 0, 0);
      acc[mt][tt] = __builtin_amdgcn_mfma_f32_16x16x32_bf16(af[tt][1], bx1, acc[mt][tt], 0, 0, 0);
      acc[mt][tt] = __builtin_amdgcn_mfma_f32_16x16x32_bf16(af[tt][2], bx2, acc[mt][tt], 0, 0, 0);
    }
  }
  float S[4][4], Q[4][4];
#pragma unroll
  for (int tt = 0; tt < 4; ++tt)
#pragma unroll
    for (int r = 0; r < 4; ++r) {
      float s = 0.f, q = 0.f;
#pragma unroll
      for (int mt = 0; mt < 8; ++mt) { float a = acc[mt][tt][r]; s += a; q += a * a; }
#pragma unroll
      for (int off = 1; off < 16; off <<= 1) { s += __shfl_xor(s, off); q += __shfl_xor(q, off); }
      S[tt][r] = s; Q[tt][r] = q;
    }
  if (lm == 0)
#pragma unroll
    for (int tt = 0; tt < 4; ++tt)
#pragma unroll
      for (int r = 0; r < 4; ++r) {
        sred[wv][tt * 16 + lq * 4 + r][0] = S[tt][r];
        sred[wv][tt * 16 + lq * 4 + r][1] = Q[tt][r];
      }
  __syncthreads();
  if (tid < 64) {
    float Sa = 0.f, Qa = 0.f;
#pragma unroll
    for (int w8 = 0; w8 < 8; ++w8) { Sa += sred[w8][tid][0]; Qa += sred[w8][tid][1]; }
    int oc = origcol(ct * 64 + tid);
    float m_ = Sa * (1.f / BB), v_ = Qa * (1.f / BB) - m_ * m_;
    float A = gih0[oc] * rsqrtf(v_ + EPSB);
    scoef[tid][0] = A; scoef[tid][1] = bih0[oc] - A * m_ + b0[oc];
  }
  __syncthreads();
  float CA[4][4], CD[4][4];
#pragma unroll
  for (int tt = 0; tt < 4; ++tt)
#pragma unroll
    for (int r = 0; r < 4; ++r) {
      CA[tt][r] = scoef[tt * 16 + lq * 4 + r][0];
      CD[tt][r] = scoef[tt * 16 + lq * 4 + r][1];
    }
#pragma unroll
  for (int mt = 0; mt < 8; ++mt) {
    const int row = R0 + mt * 16 + lm;
#pragma unroll
    for (int tt = 0; tt < 4; ++tt) {
      const int g = ct * 4 + tt;
      u32 lo = (u32)f2bf(CA[tt][0] * acc[mt][tt][0] + CD[tt][0])
             | ((u32)f2bf(CA[tt][1] * acc[mt][tt][1] + CD[tt][1]) << 16);
      u32 hi = (u32)f2bf(CA[tt][2] * acc[mt][tt][2] + CD[tt][2])
             | ((u32)f2bf(CA[tt][3] * acc[mt][tt][3] + CD[tt][3]) << 16);
      g_G1[(((size_t)t * 32 + g) * BB + row) * 4 + lq] = (u64)lo | ((u64)hi << 32);
    }
  }
}

// ---- krec3: col-owner + batch-quarter persistent recurrence.
// 256 blocks x 512 thr = 1 block/CU. Block = (L = bid>>7, g = (bid>>2)&31, q = bid&3).
// Owns cols [g*16, g*16+16) x rows [q*256, q*256+256). BN reduce = 4-sibling
// exchange of 128 B partials (1 flag round each for gates and c). h-ready is a
// 32-flag AND per quarter, aggregated by the g==0 block into one generation word.
// Race-freedom of the un-timestamped g_gp/g_cp mailboxes: a block's step-(t+1)
// partial write is gated (through its GEMM) on every sibling's step-t END flag
// (F3/F4 for gates via h, F1 for c via coefs), which each sibling publishes only
// AFTER consuming step-t partials. All flags advance exactly TT per launch.
__global__ __launch_bounds__(512, 2) void krec3(
    const float* __restrict__ ghh0, const float* __restrict__ bhh0,
    const float* __restrict__ gc0,  const float* __restrict__ bc0,
    const float* __restrict__ gih1, const float* __restrict__ bih1,
    const float* __restrict__ ghh1, const float* __restrict__ bhh1,
    const float* __restrict__ b1,   const float* __restrict__ gc1,
    const float* __restrict__ bc1) {
  const int bid = blockIdx.x;
  const int L = bid >> 7, g = (bid >> 2) & 31, q = bid & 3;
  const int tid = threadIdx.x, w = tid >> 6, l = tid & 63;
  const int lm = l & 15, lq = l >> 4;
  const int rbase = q * 256 + w * 32;        // wave's rows: rbase + mt*16 + lm

  __shared__ float s_red[8][16][4];
  __shared__ float s_coef[16][3];
  __shared__ float s_cred[8][4][2];
  __shared__ float s_ccoef[4][2];
  __shared__ float s_gamA[16], s_gamB[16], s_bs[16], s_cg[4], s_cb[4];
  __shared__ u32 s_base;

  if (tid == 0) s_base = aload(&g_F1[L][g][q]);   // own flag -> epoch base (TT*n)
  if (tid < 16) {
    const int oc = origcol(g * 16 + tid);
    if (L == 0) { s_gamA[tid] = ghh0[oc]; s_bs[tid] = bhh0[oc]; }
    else { s_gamA[tid] = gih1[oc]; s_gamB[tid] = ghh1[oc];
           s_bs[tid] = bih1[oc] + bhh1[oc] + b1[oc]; }
  }
  if (tid < 4) {
    s_cg[tid] = (L ? gc1 : gc0)[g * 4 + tid];
    s_cb[tid] = (L ? bc1 : bc0)[g * 4 + tid];
  }
  __syncthreads();
  const u32 base = s_base;

  // persistent weight fragments (16 cols): A-stream and (L1) B-stream
  v8s afA[4], afB[4];
  {
    const ush* wA = (L == 0) ? g_wthh0 : g_wtih1;
#pragma unroll
    for (int ks = 0; ks < 4; ++ks) {
      afA[ks] = ld8(&wA[(g * 16 + lm) * HH + ks * 32 + lq * 8]);
      if (L == 1) afB[ks] = ld8(&g_wthh1[(g * 16 + lm) * HH + ks * 32 + lq * 8]);
    }
  }

  const ush* const h0r = reinterpret_cast<const ush*>(g_h0s);
  const ush* const h1r = reinterpret_cast<const ush*>(g_h1s);
  float* const gpO = g_gp + ((L * 32 + g) * 4 + q) * 64;
  float* const cpO = g_cp + ((L * 32 + g) * 4 + q) * 16;

  float creg[2] = {0.f, 0.f}, so_[2] = {0.f, 0.f};
  const v4f vz = {0.f, 0.f, 0.f, 0.f};

#pragma unroll 1
  for (int t = 0; t < TT; ++t) {
    v4f PA[2] = {vz, vz}, PB[2] = {vz, vz};
    u64 g1v[2] = {0, 0};

    if (L == 0) {
      // G1 prefetch (flag-independent; launch-constant data, safe across fences)
#pragma unroll
      for (int mt = 0; mt < 2; ++mt)
        g1v[mt] = g_G1[(((size_t)t * 32 + g) * BB + rbase + mt * 16 + lm) * 4 + lq];
      if (t > 0) {
        if (g == 0) {
          if (tid < 32) pollge(&g_F3[q][tid], base + t);
          __syncthreads();
          if (tid == 0) astore(&g_agg[q][0], base + t);
        } else {
          if (tid == 0) pollge(&g_agg[q][0], base + t);
          __syncthreads();
        }
        __threadfence();
        const ush* hb = h0r + (size_t)(t - 1) * BB * HH;
#pragma unroll
        for (int mt = 0; mt < 2; ++mt) {
          const ush* hp = hb + (size_t)(rbase + mt * 16 + lm) * HH + lq * 8;
#pragma unroll
          for (int ks = 0; ks < 4; ++ks)
            PA[mt] = __builtin_amdgcn_mfma_f32_16x16x32_bf16(afA[ks], ld8(hp + ks * 32), PA[mt], 0, 0, 0);
        }
      }
    } else {
      // (1) hh1-GEMM on h1[t-1] (overlaps L0 finishing h0[t])
      if (t > 0) {
        if (g == 0) {
          if (tid < 32) pollge(&g_F4[q][tid], base + t);
          __syncthreads();
          if (tid == 0) astore(&g_agg[q][2], base + t);
        } else {
          if (tid == 0) pollge(&g_agg[q][2], base + t);
          __syncthreads();
        }
        __threadfence();
        const ush* hb = h1r + (size_t)(t - 1) * BB * HH;
#pragma unroll
        for (int mt = 0; mt < 2; ++mt) {
          const ush* hp = hb + (size_t)(rbase + mt * 16 + lm) * HH + lq * 8;
#pragma unroll
          for (int ks = 0; ks < 4; ++ks)
            PB[mt] = __builtin_amdgcn_mfma_f32_16x16x32_bf16(afB[ks], ld8(hp + ks * 32), PB[mt], 0, 0, 0);
        }
      }
      // (2) ih1-GEMM on h0[t]
      if (g == 0) {
        if (tid < 32) pollge(&g_F3[q][tid], base + t + 1);
        __syncthreads();
        if (tid == 0) astore(&g_agg[q][1], base + t + 1);
      } else {
        if (tid == 0) pollge(&g_agg[q][1], base + t + 1);
        __syncthreads();
      }
      __threadfence();
      const ush* hb = h0r + (size_t)t * BB * HH;
#pragma unroll
      for (int mt = 0; mt < 2; ++mt) {
        const ush* hp = hb + (size_t)(rbase + mt * 16 + lm) * HH + lq * 8;
#pragma unroll
        for (int ks = 0; ks < 4; ++ks)
          PA[mt] = __builtin_amdgcn_mfma_f32_16x16x32_bf16(afA[ks], ld8(hp + ks * 32), PA[mt], 0, 0, 0);
      }
    }

    // ---- gate stats over own 256 rows (per col) ----
#pragma unroll
    for (int r = 0; r < 4; ++r) {
      float s1 = PA[0][r] + PA[1][r];
      float q1 = PA[0][r] * PA[0][r] + PA[1][r] * PA[1][r];
      float s2 = PB[0][r] + PB[1][r];
      float q2 = PB[0][r] * PB[0][r] + PB[1][r] * PB[1][r];
#pragma unroll
      for (int off = 1; off < 16; off <<= 1) {
        s1 += __shfl_xor(s1, off); q1 += __shfl_xor(q1, off);
        if (L == 1) { s2 += __shfl_xor(s2, off); q2 += __shfl_xor(q2, off); }
      }
      if (lm == 0) {
        s_red[w][lq * 4 + r][0] = s1; s_red[w][lq * 4 + r][1] = q1;
        if (L == 1) { s_red[w][lq * 4 + r][2] = s2; s_red[w][lq * 4 + r][3] = q2; }
      }
    }
    __syncthreads();
    if (tid < 16) {
      float S1 = 0.f, Q1 = 0.f, S2 = 0.f, Q2 = 0.f;
#pragma unroll
      for (int w8 = 0; w8 < 8; ++w8) {
        S1 += s_red[w8][tid][0]; Q1 += s_red[w8][tid][1];
        if (L == 1) { S2 += s_red[w8][tid][2]; Q2 += s_red[w8][tid][3]; }
      }
      gpO[tid * 2] = S1; gpO[tid * 2 + 1] = Q1;
      if (L == 1) { gpO[32 + tid * 2] = S2; gpO[33 + tid * 2] = Q2; }
    }
    __syncthreads();
    if (tid == 0) { __threadfence(); astore(&g_F1[L][g][q], base + t + 1); }
    if (tid < 4 && tid != q) pollge(&g_F1[L][g][tid], base + t + 1);
    __syncthreads();
    __threadfence();
    if (tid < 16) {
      float S1 = 0.f, Q1 = 0.f, S2 = 0.f, Q2 = 0.f;
#pragma unroll
      for (int q2i = 0; q2i < 4; ++q2i) {
        const float* gp2 = g_gp + ((L * 32 + g) * 4 + q2i) * 64;
        S1 += gp2[tid * 2]; Q1 += gp2[tid * 2 + 1];
        if (L == 1) { S2 += gp2[32 + tid * 2]; Q2 += gp2[33 + tid * 2]; }
      }
      const float mu1 = S1 * (1.f / BB), v1 = Q1 * (1.f / BB) - mu1 * mu1;
      const float A1 = s_gamA[tid] * rsqrtf(v1 + EPSB);
      if (L == 0) {
        s_coef[tid][0] = A1; s_coef[tid][1] = 0.f; s_coef[tid][2] = s_bs[tid] - A1 * mu1;
      } else {
        const float mu2 = S2 * (1.f / BB), v2 = Q2 * (1.f / BB) - mu2 * mu2;
        const float A2 = s_gamB[tid] * rsqrtf(v2 + EPSB);
        s_coef[tid][0] = A1; s_coef[tid][1] = A2;
        s_coef[tid][2] = s_bs[tid] - A1 * mu1 - A2 * mu2;
      }
    }
    __syncthreads();

    // ---- pointwise + c update ----
    float CA[4], CB[4], CD[4];
#pragma unroll
    for (int r = 0; r < 4; ++r) {
      CA[r] = s_coef[lq * 4 + r][0];
      CB[r] = s_coef[lq * 4 + r][1];
      CD[r] = s_coef[lq * 4 + r][2];
    }
#pragma unroll
    for (int mt = 0; mt < 2; ++mt) {
      float gv[4];
      if (L == 0) {
        const u64 g1 = g1v[mt];
        gv[0] = bf2f((ush)g1)         + CA[0] * PA[mt][0] + CD[0];
        gv[1] = bf2f((ush)(g1 >> 16)) + CA[1] * PA[mt][1] + CD[1];
        gv[2] = bf2f((ush)(g1 >> 32)) + CA[2] * PA[mt][2] + CD[2];
        gv[3] = bf2f((ush)(g1 >> 48)) + CA[3] * PA[mt][3] + CD[3];
      } else {
#pragma unroll
        for (int r = 0; r < 4; ++r)
          gv[r] = CA[r] * PA[mt][r] + CB[r] * PB[mt][r] + CD[r];
      }
      const float cold = (t == 0) ? 0.f : creg[mt];
      const float c1 = sigf(gv[0]) * cold + sigf(gv[1]) * tanhf_(gv[3]);
      creg[mt] = c1; so_[mt] = sigf(gv[2]);
    }

    // ---- c stats (per unit over own 256 rows) ----
    {
      float cs = creg[0] + creg[1];
      float cq = creg[0] * creg[0] + creg[1] * creg[1];
#pragma unroll
      for (int off = 1; off < 16; off <<= 1) { cs += __shfl_xor(cs, off); cq += __shfl_xor(cq, off); }
      if (lm == 0) { s_cred[w][lq][0] = cs; s_cred[w][lq][1] = cq; }
    }
    __syncthreads();
    if (tid < 4) {
      float S = 0.f, Q = 0.f;
#pragma unroll
      for (int w8 = 0; w8 < 8; ++w8) { S += s_cred[w8][tid][0]; Q += s_cred[w8][tid][1]; }
      cpO[tid * 2] = S; cpO[tid * 2 + 1] = Q;
    }
    __syncthreads();
    if (tid == 0) { __threadfence(); astore(&g_F2[L][g][q], base + t + 1); }
    if (tid < 4 && tid != q) pollge(&g_F2[L][g][tid], base + t + 1);
    __syncthreads();
    __threadfence();
    if (tid < 4) {
      float S = 0.f, Q = 0.f;
#pragma unroll
      for (int q2i = 0; q2i < 4; ++q2i) {
        const float* cp2 = g_cp + ((L * 32 + g) * 4 + q2i) * 16;
        S += cp2[tid * 2]; Q += cp2[tid * 2 + 1];
      }
      const float mu = S * (1.f / BB), var = Q * (1.f / BB) - mu * mu;
      const float ac = s_cg[tid] * rsqrtf(var + EPSB);
      s_ccoef[tid][0] = ac; s_ccoef[tid][1] = s_cb[tid] - ac * mu;
    }
    __syncthreads();
    const float ac = s_ccoef[lq][0], dc = s_ccoef[lq][1];

    // ---- h output: pack 4 units across lq lanes -> u64 store per row ----
    u64* hdst = ((L == 0) ? g_h0s : g_h1s) + (size_t)t * BB * 32;
#pragma unroll
    for (int mt = 0; mt < 2; ++mt) {
      const int row = rbase + mt * 16 + lm;
      const u32 v = (u32)f2bf(so_[mt] * tanhf_(ac * creg[mt] + dc));
      const u32 a = v | (__shfl_xor(v, 16) << 16);
      const u32 b2 = __shfl_xor(a, 32);
      if (lq == 0) hdst[(size_t)row * 32 + g] = (u64)a | ((u64)b2 << 32);
    }
    __syncthreads();                 // drains h stores (barrier implies vmcnt(0))
    if (tid == 0) {
      __threadfence();
      astore((L == 0) ? &g_F3[q][g] : &g_F4[q][g], base + t + 1);
    }
  }
}

// ---- epilogue: emb = h1(T-1) @ fc_w + fc_b (bf16 out) ----
__global__ __launch_bounds__(256) void kfc(const float* __restrict__ fcb) {
  const int tid = threadIdx.x, w = tid >> 6, l = tid & 63;
  const int lm = l & 15, lq = l >> 4;
  const int col = blockIdx.x * 16 + lm;   // grid 16
  const ush* hsrc = reinterpret_cast<const ush*>(g_h1s) + (size_t)(TT - 1) * BB * HH;
  v8s bf[4];
#pragma unroll
  for (int ks = 0; ks < 4; ++ks) bf[ks] = ld8(&g_fcwt[col * HH + ks * 32 + lq * 8]);
  const float bias = fcb[col];
  const v4f vz = {0.f, 0.f, 0.f, 0.f};
#pragma unroll
  for (int mt = 0; mt < 16; ++mt) {
    const int rowa = w * 256 + mt * 16 + lm;
    const ush* ap = hsrc + (size_t)rowa * HH + lq * 8;
    v4f acc = vz;
#pragma unroll
    for (int ks = 0; ks < 4; ++ks)
      acc = __builtin_amdgcn_mfma_f32_16x16x32_bf16(ld8(ap + ks * 32), bf[ks], acc, 0, 0, 0);
#pragma unroll
    for (int r = 0; r < 4; ++r) {
      int row = w * 256 + mt * 16 + lq * 4 + r;
      g_emb[row * OUTN + col] = f2bf(acc[r] + bias);
    }
  }
}

// ---- epilogue: out = emb @ dec_w + dec_b, transposed MFMA -> 16B coalesced stores ----
__global__ __launch_bounds__(256) void kdec(const float* __restrict__ decb, float* __restrict__ out) {
  const int tid = threadIdx.x, wv = tid >> 6, l = tid & 63;
  const int lm = l & 15, lq = l >> 4;
  const int c0 = blockIdx.x * 16;         // grid 600
  const int R0 = wv * 256;
  v8s af[8];
#pragma unroll
  for (int ks = 0; ks < 8; ++ks) af[ks] = ld8(&g_decwt[(size_t)(c0 + lm) * OUTN + ks * 32 + lq * 8]);
  float bias[4];
#pragma unroll
  for (int r = 0; r < 4; ++r) bias[r] = decb[c0 + lq * 4 + r];
  const v4f vz = {0.f, 0.f, 0.f, 0.f};
#pragma unroll
  for (int mt = 0; mt < 16; ++mt) {
    const int row = R0 + mt * 16 + lm;
    const ush* bp = g_emb + (size_t)row * OUTN + lq * 8;
    v4f acc = vz;
#pragma unroll
    for (int ks = 0; ks < 8; ++ks)
      acc = __builtin_amdgcn_mfma_f32_16x16x32_bf16(af[ks], ld8(bp + ks * 32), acc, 0, 0, 0);
    v4f o;
#pragma unroll
    for (int r = 0; r < 4; ++r) o[r] = acc[r] + bias[r];
    *reinterpret_cast<v4f*>(&out[(size_t)row * DECN + c0 + lq * 4]) = o;
  }
}

extern "C" void kernel_launch(void* const* d_in, const int* in_sizes, int n_in,
                              void* d_out, int out_size, void* d_ws, size_t ws_size,
                              hipStream_t stream) {
  const float* seq  = (const float*)d_in[0];
  const float* Wih0 = (const float*)d_in[1];
  const float* Whh0 = (const float*)d_in[2];
  const float* b0   = (const float*)d_in[3];
  const float* gih0 = (const float*)d_in[4];
  const float* bih0 = (const float*)d_in[5];
  const float* ghh0 = (const float*)d_in[6];
  const float* bhh0 = (const float*)d_in[7];
  const float* gc0  = (const float*)d_in[8];
  const float* bc0  = (const float*)d_in[9];
  const float* Wih1 = (const float*)d_in[10];
  const float* Whh1 = (const float*)d_in[11];
  const float* b1   = (const float*)d_in[12];
  const float* gih1 = (const float*)d_in[13];
  const float* bih1 = (const float*)d_in[14];
  const float* ghh1 = (const float*)d_in[15];
  const float* bhh1 = (const float*)d_in[16];
  const float* gc1  = (const float*)d_in[17];
  const float* bc1  = (const float*)d_in[18];
  const float* fcw  = (const float*)d_in[19];
  const float* fcb  = (const float*)d_in[20];
  const float* decw = (const float*)d_in[21];
  const float* decb = (const float*)d_in[22];
  float* out = (float*)d_out;
  (void)in_sizes; (void)n_in; (void)out_size; (void)d_ws; (void)ws_size;

  kpackx<<<dim3((TT * BB * KXP) / 256), dim3(256), 0, stream>>>(seq);
  kpackw<<<dim3(10688), dim3(256), 0, stream>>>(Wih0, Whh0, Wih1, Whh1, fcw, decw);
  kprep<<<dim3(TT * 8), dim3(512), 0, stream>>>(gih0, bih0, b0);
  krec3<<<dim3(256), dim3(512), 0, stream>>>(ghh0, bhh0, gc0, bc0,
                                             gih1, bih1, ghh1, bhh1, b1, gc1, bc1);
  kfc<<<dim3(16), dim3(256), 0, stream>>>(fcb);
  kdec<<<dim3(600), dim3(256), 0, stream>>>(decb, out);
}

// Round 4
// 4007.249 us; speedup vs baseline: 4.6201x; 4.6201x over previous
//
#include <hip/hip_runtime.h>
#include <stdint.h>
#include <stddef.h>

#define TT   128
#define BB   1024
#define INN  75
#define HH   128
#define KXP  96
#define OUTN 256
#define DECN 9600
#define EPSB 1e-5f
#define NRB  16          // row-blocks per mesh
#define RWS  64          // rows per block

typedef short v8s __attribute__((ext_vector_type(8)));   // 8 bf16 (4 VGPR) MFMA frag
typedef float v4f __attribute__((ext_vector_type(4)));   // 4 fp32 acc frag
typedef float v2f __attribute__((ext_vector_type(2)));
typedef unsigned short ush;
typedef unsigned int   u32;
typedef unsigned long long u64;

#define MFMA(A,B,C) __builtin_amdgcn_mfma_f32_16x16x32_bf16((A),(B),(C),0,0,0)

// ---- static device workspace (fully rewritten every launch) ----
__device__ __align__(256) ush g_xpad[(size_t)TT * BB * KXP];   // x padded to K=96, [t][b][k] bf16
__device__ __align__(256) u64 g_G1[(size_t)TT * 32 * BB * 4];  // BN(x@Wih0)+b0, [t][g][row][16 bf16]
__device__ __align__(256) u64 g_h0s[(size_t)TT * BB * 32];     // h0 stream [t][row][128 bf16] as u64
__device__ __align__(256) u64 g_h1s[(size_t)TT * BB * 32];     // h1 stream
// weights [m][k] bf16, m permuted: origcol(m) = (m&3)*128 + (m>>4)*4 + ((m>>2)&3)
__device__ __align__(256) ush g_wtih0[512 * KXP];
__device__ __align__(256) ush g_wthh0[512 * HH];
__device__ __align__(256) ush g_wtih1[512 * HH];
__device__ __align__(256) ush g_wthh1[512 * HH];
__device__ __align__(256) ush g_fcwt[OUTN * HH];               // fc_w^T [col][k]
__device__ __align__(256) ush g_decwt[(size_t)DECN * OUTN];    // dec_w^T [col][k]
__device__ __align__(256) ush g_emb[BB * OUTN];                // fc output bf16

// ---- sync state: monotone u32 counters, each += TT per launch (replay-safe).
// Flags padded to 128 B apart. mesh = L*2+H (4 meshes x 16 row-blocks).
__device__ u32 g_F1[4 * NRB * 32];     // gate partials published (mesh, rb)
__device__ u32 g_F2[4 * NRB * 32];     // c partials published
__device__ u32 g_F3[2 * NRB * 32];     // h0[t] published by L0 (H, rb)
__device__ u32 g_F4[2 * NRB * 32];     // h1[t] published by L1 (H, rb)
// parity (t&1) double-buffered partial mailboxes.
// Safety: block writes parity p at step t, rewrites p at t+2; any consumer has
// read step-t data before it can publish step t+1 partials, and the writer's
// t+2 progress is gated on all consumers' t+1 publications via the flag rounds.
__device__ __align__(256) float g_gp[4 * NRB * 2 * 1024];  // [(mesh,rb),par][A:512 | B:512]
__device__ __align__(256) float g_cp[4 * NRB * 2 * 128];   // [(mesh,rb),par][64 units x S,Q]

// ---- helpers ----
__device__ __forceinline__ ush f2bf(float f) {
  u32 u = __float_as_uint(f);
  u32 r = (u + 0x7FFFu + ((u >> 16) & 1u)) >> 16;   // RNE
  return (ush)r;
}
__device__ __forceinline__ float bf2f(ush u) { return __uint_as_float(((u32)u) << 16); }
__device__ __forceinline__ float sigf(float x)  { return 1.f / (1.f + __expf(-x)); }
__device__ __forceinline__ float tanhf_(float x){ float e = __expf(2.f * x); return 1.f - 2.f / (e + 1.f); }
__device__ __forceinline__ v8s ld8(const ush* p) { return *reinterpret_cast<const v8s*>(p); }
__device__ __forceinline__ int origcol(int m) { return (m & 3) * 128 + (m >> 4) * 4 + ((m >> 2) & 3); }

__device__ __forceinline__ u32 aload(const u32* p) {
  return __hip_atomic_load(p, __ATOMIC_RELAXED, __HIP_MEMORY_SCOPE_AGENT);
}
__device__ __forceinline__ void astore(u32* p, u32 v) {
  __hip_atomic_store(p, v, __ATOMIC_RELAXED, __HIP_MEMORY_SCOPE_AGENT);
}
__device__ __forceinline__ void pollge(const u32* p, u32 tgt) {
  while (aload(p) < tgt) __builtin_amdgcn_s_sleep(2);
}

// ---- prep kernels (unchanged, verified) ----
__global__ void kpackx(const float* __restrict__ seq) {
  int idx = blockIdx.x * 256 + threadIdx.x;   // < TT*BB*KXP
  int kk = idx % KXP; int rest = idx / KXP;
  int b = rest % BB;  int t = rest / BB;
  float v = (kk < INN) ? seq[((size_t)b * TT + t) * INN + kk] : 0.f;
  g_xpad[idx] = f2bf(v);
}

__global__ void kpackw(const float* __restrict__ Wih0, const float* __restrict__ Whh0,
                       const float* __restrict__ Wih1, const float* __restrict__ Whh1,
                       const float* __restrict__ fcw,  const float* __restrict__ decw) {
  int idx = blockIdx.x * 256 + threadIdx.x;   // grid 10688
  if (idx < 49152) {                          // wtih0: [m][96]
    int m = idx / KXP, k = idx % KXP;
    g_wtih0[idx] = f2bf((k < INN) ? Wih0[k * 512 + origcol(m)] : 0.f);
  } else if (idx < 114688) {
    int j = idx - 49152; int m = j / HH, k = j % HH;
    g_wthh0[j] = f2bf(Whh0[k * 512 + origcol(m)]);
  } else if (idx < 180224) {
    int j = idx - 114688; int m = j / HH, k = j % HH;
    g_wtih1[j] = f2bf(Wih1[k * 512 + origcol(m)]);
  } else if (idx < 245760) {
    int j = idx - 180224; int m = j / HH, k = j % HH;
    g_wthh1[j] = f2bf(Whh1[k * 512 + origcol(m)]);
  } else if (idx < 278528) {                  // fcwt [c][128]
    int j = idx - 245760; int c = j / HH, k = j % HH;
    g_fcwt[j] = f2bf(fcw[k * OUTN + c]);
  } else {                                    // decwt [c][256], coalesced reads
    int j = idx - 278528; int n = j % DECN, k = j / DECN;
    g_decwt[(size_t)n * OUTN + k] = f2bf(decw[(size_t)k * DECN + n]);
  }
}

// G1[t][g][row][16] = BN_ih0(x_t @ Wih0) + b0 (folded), transposed-MFMA orientation.
__global__ __launch_bounds__(512) void kprep(const float* __restrict__ gih0,
                                             const float* __restrict__ bih0,
                                             const float* __restrict__ b0) {
  const int t = blockIdx.x >> 3, ct = blockIdx.x & 7;
  const int tid = threadIdx.x, wv = tid >> 6, l = tid & 63;
  const int lm = l & 15, lq = l >> 4;
  const int R0 = wv * 128;
  __shared__ float sred[8][64][2];
  __shared__ float scoef[64][2];

  v8s af[4][3];
#pragma unroll
  for (int tt = 0; tt < 4; ++tt)
#pragma unroll
    for (int ks = 0; ks < 3; ++ks)
      af[tt][ks] = ld8(&g_wtih0[(ct * 64 + tt * 16 + lm) * KXP + ks * 32 + lq * 8]);

  const v4f vz = {0.f, 0.f, 0.f, 0.f};
  v4f acc[8][4];
#pragma unroll
  for (int mt = 0; mt < 8; ++mt)
#pragma unroll
    for (int tt = 0; tt < 4; ++tt) acc[mt][tt] = vz;

#pragma unroll
  for (int mt = 0; mt < 8; ++mt) {
    const ush* xr = g_xpad + ((size_t)t * BB + R0 + mt * 16 + lm) * KXP + lq * 8;
    v8s bx0 = ld8(xr), bx1 = ld8(xr + 32), bx2 = ld8(xr + 64);
#pragma unroll
    for (int tt = 0; tt < 4; ++tt) {
      acc[mt][tt] = MFMA(af[tt][0], bx0, acc[mt][tt]);
      acc[mt][tt] = MFMA(af[tt][1], bx1, acc[mt][tt]);
      acc[mt][tt] = MFMA(af[tt][2], bx2, acc[mt][tt]);
    }
  }
  float S[4][4], Q[4][4];
#pragma unroll
  for (int tt = 0; tt < 4; ++tt)
#pragma unroll
    for (int r = 0; r < 4; ++r) {
      float s = 0.f, q = 0.f;
#pragma unroll
      for (int mt = 0; mt < 8; ++mt) { float a = acc[mt][tt][r]; s += a; q += a * a; }
#pragma unroll
      for (int off = 1; off < 16; off <<= 1) { s += __shfl_xor(s, off); q += __shfl_xor(q, off); }
      S[tt][r] = s; Q[tt][r] = q;
    }
  if (lm == 0)
#pragma unroll
    for (int tt = 0; tt < 4; ++tt)
#pragma unroll
      for (int r = 0; r < 4; ++r) {
        sred[wv][tt * 16 + lq * 4 + r][0] = S[tt][r];
        sred[wv][tt * 16 + lq * 4 + r][1] = Q[tt][r];
      }
  __syncthreads();
  if (tid < 64) {
    float Sa = 0.f, Qa = 0.f;
#pragma unroll
    for (int w8 = 0; w8 < 8; ++w8) { Sa += sred[w8][tid][0]; Qa += sred[w8][tid][1]; }
    int oc = origcol(ct * 64 + tid);
    float m_ = Sa * (1.f / BB), v_ = Qa * (1.f / BB) - m_ * m_;
    float A = gih0[oc] * rsqrtf(v_ + EPSB);
    scoef[tid][0] = A; scoef[tid][1] = bih0[oc] - A * m_ + b0[oc];
  }
  __syncthreads();
  float CA[4][4], CD[4][4];
#pragma unroll
  for (int tt = 0; tt < 4; ++tt)
#pragma unroll
    for (int r = 0; r < 4; ++r) {
      CA[tt][r] = scoef[tt * 16 + lq * 4 + r][0];
      CD[tt][r] = scoef[tt * 16 + lq * 4 + r][1];
    }
#pragma unroll
  for (int mt = 0; mt < 8; ++mt) {
    const int row = R0 + mt * 16 + lm;
#pragma unroll
    for (int tt = 0; tt < 4; ++tt) {
      const int g = ct * 4 + tt;
      u32 lo = (u32)f2bf(CA[tt][0] * acc[mt][tt][0] + CD[tt][0])
             | ((u32)f2bf(CA[tt][1] * acc[mt][tt][1] + CD[tt][1]) << 16);
      u32 hi = (u32)f2bf(CA[tt][2] * acc[mt][tt][2] + CD[tt][2])
             | ((u32)f2bf(CA[tt][3] * acc[mt][tt][3] + CD[tt][3]) << 16);
      g_G1[(((size_t)t * 32 + g) * BB + row) * 4 + lq] = (u64)lo | ((u64)hi << 32);
    }
  }
}

// ---- krec4: row-owner, half-col-split persistent recurrence.
// 64 blocks x 512 thr. Block = (L = bid>>5, H = (bid>>4)&1, rb = bid&15):
// rows [rb*64, rb*64+64) x m-cols [H*256, H*256+256) = 64 complete units.
// Weights in registers; h via t-indexed global streams (block reads ONLY its
// own 64 rows -> no broadcast). Per step: GEMM -> wave-local stats (full 64
// rows per wave) -> publish 2-4 KB partial -> mesh flag round (16 blocks) ->
// all re-read 15 partials, coefs -> pointwise -> c-partials -> 2nd flag round
// -> c-coefs -> h compute -> publish h + F3/F4. 2 mesh RTTs + p2p h flags/step.
// Lane map: row = rb*64 + mt*16 + lm; unit_local = (w*2+ct)*4+lq; gate = r.
__global__ __launch_bounds__(512, 2) void krec4(
    const float* __restrict__ ghh0, const float* __restrict__ bhh0,
    const float* __restrict__ gc0,  const float* __restrict__ bc0,
    const float* __restrict__ gih1, const float* __restrict__ bih1,
    const float* __restrict__ ghh1, const float* __restrict__ bhh1,
    const float* __restrict__ b1,   const float* __restrict__ gc1,
    const float* __restrict__ bc1) {
  const int bid = blockIdx.x;            // 0..63
  const int L = bid >> 5, H = (bid >> 4) & 1, rb = bid & 15;
  const int mesh = L * 2 + H;
  const int tid = threadIdx.x, w = tid >> 6, l = tid & 63;
  const int lm = l & 15, lq = l >> 4;
  const int R0 = rb * RWS;

  __shared__ float s_gA[256], s_gB[256], s_bs[256];
  __shared__ float s_cgM[64], s_cbM[64];
  __shared__ float s_cA[256], s_cB[256], s_cD[256], s_mual[2][256];
  __shared__ float s_ccA[64], s_ccD[64];
  __shared__ u32 s_base;

  if (tid == 0) s_base = aload(&g_F1[(mesh * NRB + rb) * 32]);   // own flag -> epoch base
  if (tid < 256) {
    const int oc = origcol(H * 256 + tid);
    if (L == 0) { s_gA[tid] = ghh0[oc]; s_gB[tid] = 0.f; s_bs[tid] = bhh0[oc]; }
    else { s_gA[tid] = gih1[oc]; s_gB[tid] = ghh1[oc];
           s_bs[tid] = bih1[oc] + bhh1[oc] + b1[oc]; }
  }
  if (tid < 64) {
    const int u = H * 64 + tid;
    s_cgM[tid] = (L ? gc1 : gc0)[u];
    s_cbM[tid] = (L ? bc1 : bc0)[u];
  }
  __syncthreads();
  const u32 base = s_base;

  // persistent weight fragments: wave w owns colTiles ct=0,1 -> cols H*256+(w*2+ct)*16..+15
  v8s afA[2][4], afB[2][4];
  {
    const ush* wA = L ? g_wtih1 : g_wthh0;
#pragma unroll
    for (int ct = 0; ct < 2; ++ct)
#pragma unroll
      for (int ks = 0; ks < 4; ++ks) {
        const int mrow = H * 256 + (w * 2 + ct) * 16 + lm;
        afA[ct][ks] = ld8(&wA[mrow * HH + ks * 32 + lq * 8]);
        if (L) afB[ct][ks] = ld8(&g_wthh1[mrow * HH + ks * 32 + lq * 8]);
      }
  }

  float* const gpO = g_gp + (size_t)(mesh * NRB + rb) * 2 * 1024;
  float* const cpO = g_cp + (size_t)(mesh * NRB + rb) * 2 * 128;
  const ush* const h0r = reinterpret_cast<const ush*>(g_h0s);
  const ush* const h1r = reinterpret_cast<const ush*>(g_h1s);

  float creg[4][2] = {{0.f,0.f},{0.f,0.f},{0.f,0.f},{0.f,0.f}};
  float so_[4][2];
  const v4f vz = {0.f, 0.f, 0.f, 0.f};

#pragma unroll 1
  for (int t = 0; t < TT; ++t) {
    const int par = t & 1;
    v4f PA[4][2], PB[4][2];
#pragma unroll
    for (int mt = 0; mt < 4; ++mt) {
      PA[mt][0] = vz; PA[mt][1] = vz; PB[mt][0] = vz; PB[mt][1] = vz;
    }
    u64 g1v[4][2];

    if (L == 0) {     // G1 prefetch (launch-constant data; issued before polls)
#pragma unroll
      for (int mt = 0; mt < 4; ++mt)
#pragma unroll
        for (int ct = 0; ct < 2; ++ct)
          g1v[mt][ct] = g_G1[(((size_t)t * 32 + H * 16 + w * 2 + ct) * BB
                              + R0 + mt * 16 + lm) * 4 + lq];
    }

    // ---- h-ready rendezvous (p2p flags) ----
    if (L == 0) {
      if (t > 0) {
        if (tid == 0) pollge(&g_F3[((1 - H) * NRB + rb) * 32], base + t);
        __syncthreads();
        __builtin_amdgcn_fence(__ATOMIC_ACQUIRE, "agent");
      }
    } else {
      if (tid < 2) pollge(&g_F3[(tid * NRB + rb) * 32], base + t + 1);
      if (tid == 2 && t > 0) pollge(&g_F4[((1 - H) * NRB + rb) * 32], base + t);
      __syncthreads();
      __builtin_amdgcn_fence(__ATOMIC_ACQUIRE, "agent");
    }

    // ---- GEMMs (B-operand = own 64 rows only) ----
    if (L == 0) {
      if (t > 0) {
        const ush* hb = h0r + (size_t)(t - 1) * BB * HH;
#pragma unroll
        for (int mt = 0; mt < 4; ++mt) {
          const ush* hp = hb + (size_t)(R0 + mt * 16 + lm) * HH + lq * 8;
          v8s f0 = ld8(hp), f1 = ld8(hp + 32), f2 = ld8(hp + 64), f3 = ld8(hp + 96);
#pragma unroll
          for (int ct = 0; ct < 2; ++ct) {
            PA[mt][ct] = MFMA(afA[ct][0], f0, PA[mt][ct]);
            PA[mt][ct] = MFMA(afA[ct][1], f1, PA[mt][ct]);
            PA[mt][ct] = MFMA(afA[ct][2], f2, PA[mt][ct]);
            PA[mt][ct] = MFMA(afA[ct][3], f3, PA[mt][ct]);
          }
        }
      }
    } else {
      const ush* hb = h0r + (size_t)t * BB * HH;
#pragma unroll
      for (int mt = 0; mt < 4; ++mt) {
        const ush* hp = hb + (size_t)(R0 + mt * 16 + lm) * HH + lq * 8;
        v8s f0 = ld8(hp), f1 = ld8(hp + 32), f2 = ld8(hp + 64), f3 = ld8(hp + 96);
#pragma unroll
        for (int ct = 0; ct < 2; ++ct) {
          PA[mt][ct] = MFMA(afA[ct][0], f0, PA[mt][ct]);
          PA[mt][ct] = MFMA(afA[ct][1], f1, PA[mt][ct]);
          PA[mt][ct] = MFMA(afA[ct][2], f2, PA[mt][ct]);
          PA[mt][ct] = MFMA(afA[ct][3], f3, PA[mt][ct]);
        }
      }
      if (t > 0) {
        const ush* hb1 = h1r + (size_t)(t - 1) * BB * HH;
#pragma unroll
        for (int mt = 0; mt < 4; ++mt) {
          const ush* hp = hb1 + (size_t)(R0 + mt * 16 + lm) * HH + lq * 8;
          v8s f0 = ld8(hp), f1 = ld8(hp + 32), f2 = ld8(hp + 64), f3 = ld8(hp + 96);
#pragma unroll
          for (int ct = 0; ct < 2; ++ct) {
            PB[mt][ct] = MFMA(afB[ct][0], f0, PB[mt][ct]);
            PB[mt][ct] = MFMA(afB[ct][1], f1, PB[mt][ct]);
            PB[mt][ct] = MFMA(afB[ct][2], f2, PB[mt][ct]);
            PB[mt][ct] = MFMA(afB[ct][3], f3, PB[mt][ct]);
          }
        }
      }
    }

    // ---- gate stats over all 64 block rows (in-reg + shfl over lm) ----
#pragma unroll
    for (int ct = 0; ct < 2; ++ct) {
      float sA[4], qA[4], sB[4], qB[4];
#pragma unroll
      for (int r = 0; r < 4; ++r) {
        float s1 = PA[0][ct][r] + PA[1][ct][r] + PA[2][ct][r] + PA[3][ct][r];
        float q1 = PA[0][ct][r]*PA[0][ct][r] + PA[1][ct][r]*PA[1][ct][r]
                 + PA[2][ct][r]*PA[2][ct][r] + PA[3][ct][r]*PA[3][ct][r];
        float s2 = PB[0][ct][r] + PB[1][ct][r] + PB[2][ct][r] + PB[3][ct][r];
        float q2 = PB[0][ct][r]*PB[0][ct][r] + PB[1][ct][r]*PB[1][ct][r]
                 + PB[2][ct][r]*PB[2][ct][r] + PB[3][ct][r]*PB[3][ct][r];
#pragma unroll
        for (int off = 1; off < 16; off <<= 1) {
          s1 += __shfl_xor(s1, off); q1 += __shfl_xor(q1, off);
          if (L) { s2 += __shfl_xor(s2, off); q2 += __shfl_xor(q2, off); }
        }
        sA[r] = s1; qA[r] = q1; sB[r] = s2; qB[r] = q2;
      }
      if (lm == 0) {
        float* p = gpO + par * 1024 + ((w * 2 + ct) * 16 + lq * 4) * 2;
        v4f a0 = {sA[0], qA[0], sA[1], qA[1]};
        v4f a1 = {sA[2], qA[2], sA[3], qA[3]};
        *reinterpret_cast<v4f*>(p) = a0;
        *reinterpret_cast<v4f*>(p + 4) = a1;
        if (L) {
          v4f b0v = {sB[0], qB[0], sB[1], qB[1]};
          v4f b1v = {sB[2], qB[2], sB[3], qB[3]};
          *reinterpret_cast<v4f*>(p + 512) = b0v;
          *reinterpret_cast<v4f*>(p + 516) = b1v;
        }
      }
    }

    // ---- mesh flag round 1 (gate partials) ----
    __syncthreads();                               // drains all waves' stores
    if (tid == 0) {
      __builtin_amdgcn_fence(__ATOMIC_RELEASE, "agent");
      astore(&g_F1[(mesh * NRB + rb) * 32], base + t + 1);
    }
    if (tid < NRB) pollge(&g_F1[(mesh * NRB + tid) * 32], base + t + 1);
    __syncthreads();
    __builtin_amdgcn_fence(__ATOMIC_ACQUIRE, "agent");

    // ---- coefs (redundant per block): thread (st, m) sums 16 partials ----
    {
      const int st = tid >> 8, m = tid & 255;
      if (st == 0 || L == 1) {
        float S = 0.f, Q = 0.f;
#pragma unroll
        for (int r2 = 0; r2 < NRB; ++r2) {
          const float* p = g_gp + (size_t)(mesh * NRB + r2) * 2 * 1024
                         + par * 1024 + st * 512 + m * 2;
          v2f v = *reinterpret_cast<const v2f*>(p);
          S += v.x; Q += v.y;
        }
        const float mu = S * (1.f / BB), var = Q * (1.f / BB) - mu * mu;
        const float A = (st ? s_gB[m] : s_gA[m]) * rsqrtf(var + EPSB);
        if (st == 0) s_cA[m] = A; else s_cB[m] = A;
        s_mual[st][m] = A * mu;
      }
    }
    __syncthreads();
    if (tid < 256) s_cD[tid] = s_bs[tid] - s_mual[0][tid] - (L ? s_mual[1][tid] : 0.f);
    __syncthreads();

    // ---- pointwise + c update (8 (row,unit) items per thread) ----
#pragma unroll
    for (int ct = 0; ct < 2; ++ct) {
      const int mb = (w * 2 + ct) * 16 + lq * 4;
      const v4f cA = *reinterpret_cast<const v4f*>(&s_cA[mb]);
      const v4f cD = *reinterpret_cast<const v4f*>(&s_cD[mb]);
      const v4f cB = *reinterpret_cast<const v4f*>(&s_cB[mb]);
      float cs = 0.f, cq = 0.f;
#pragma unroll
      for (int mt = 0; mt < 4; ++mt) {
        float gv[4];
        if (L == 0) {
          const u64 g1 = g1v[mt][ct];
          gv[0] = bf2f((ush)g1)         + cA[0] * PA[mt][ct][0] + cD[0];
          gv[1] = bf2f((ush)(g1 >> 16)) + cA[1] * PA[mt][ct][1] + cD[1];
          gv[2] = bf2f((ush)(g1 >> 32)) + cA[2] * PA[mt][ct][2] + cD[2];
          gv[3] = bf2f((ush)(g1 >> 48)) + cA[3] * PA[mt][ct][3] + cD[3];
        } else {
#pragma unroll
          for (int r = 0; r < 4; ++r)
            gv[r] = cA[r] * PA[mt][ct][r] + cB[r] * PB[mt][ct][r] + cD[r];
        }
        const float cold = (t == 0) ? 0.f : creg[mt][ct];
        const float c1 = sigf(gv[0]) * cold + sigf(gv[1]) * tanhf_(gv[3]);
        creg[mt][ct] = c1; so_[mt][ct] = sigf(gv[2]);
        cs += c1; cq += c1 * c1;
      }
#pragma unroll
      for (int off = 1; off < 16; off <<= 1) { cs += __shfl_xor(cs, off); cq += __shfl_xor(cq, off); }
      if (lm == 0) {
        v2f v = {cs, cq};
        *reinterpret_cast<v2f*>(&cpO[par * 128 + ((w * 2 + ct) * 4 + lq) * 2]) = v;
      }
    }

    // ---- mesh flag round 2 (c partials) ----
    __syncthreads();
    if (tid == 0) {
      __builtin_amdgcn_fence(__ATOMIC_RELEASE, "agent");
      astore(&g_F2[(mesh * NRB + rb) * 32], base + t + 1);
    }
    if (tid < NRB) pollge(&g_F2[(mesh * NRB + tid) * 32], base + t + 1);
    __syncthreads();
    __builtin_amdgcn_fence(__ATOMIC_ACQUIRE, "agent");

    if (tid < 64) {
      float S = 0.f, Q = 0.f;
#pragma unroll
      for (int r2 = 0; r2 < NRB; ++r2) {
        const float* p = g_cp + (size_t)(mesh * NRB + r2) * 2 * 128 + par * 128 + tid * 2;
        v2f v = *reinterpret_cast<const v2f*>(p);
        S += v.x; Q += v.y;
      }
      const float mu = S * (1.f / BB), var = Q * (1.f / BB) - mu * mu;
      const float ac = s_cgM[tid] * rsqrtf(var + EPSB);
      s_ccA[tid] = ac; s_ccD[tid] = s_cbM[tid] - ac * mu;
    }
    __syncthreads();

    // ---- h output: pack 4 units across lq lanes -> u64 store per row ----
    u64* hdst = (L ? g_h1s : g_h0s) + (size_t)t * BB * 32;
#pragma unroll
    for (int ct = 0; ct < 2; ++ct) {
      const int ul = (w * 2 + ct) * 4 + lq;
      const float ac = s_ccA[ul], dc = s_ccD[ul];
#pragma unroll
      for (int mt = 0; mt < 4; ++mt) {
        const u32 v = (u32)f2bf(so_[mt][ct] * tanhf_(ac * creg[mt][ct] + dc));
        const u32 a = v | (__shfl_xor(v, 16) << 16);
        const u32 b2 = __shfl_xor(a, 32);
        if (lq == 0)
          hdst[(size_t)(R0 + mt * 16 + lm) * 32 + H * 16 + (w * 2 + ct)]
              = (u64)a | ((u64)b2 << 32);
      }
    }
    __syncthreads();                               // drains h stores
    if (tid == 0) {
      __builtin_amdgcn_fence(__ATOMIC_RELEASE, "agent");
      astore(L ? &g_F4[(H * NRB + rb) * 32] : &g_F3[(H * NRB + rb) * 32], base + t + 1);
    }
  }
}

// ---- epilogue: emb = h1(T-1) @ fc_w + fc_b (bf16 out) ----
__global__ __launch_bounds__(256) void kfc(const float* __restrict__ fcb) {
  const int tid = threadIdx.x, w = tid >> 6, l = tid & 63;
  const int lm = l & 15, lq = l >> 4;
  const int col = blockIdx.x * 16 + lm;   // grid 16
  const ush* hsrc = reinterpret_cast<const ush*>(g_h1s) + (size_t)(TT - 1) * BB * HH;
  v8s bf[4];
#pragma unroll
  for (int ks = 0; ks < 4; ++ks) bf[ks] = ld8(&g_fcwt[col * HH + ks * 32 + lq * 8]);
  const float bias = fcb[col];
  const v4f vz = {0.f, 0.f, 0.f, 0.f};
#pragma unroll
  for (int mt = 0; mt < 16; ++mt) {
    const int rowa = w * 256 + mt * 16 + lm;
    const ush* ap = hsrc + (size_t)rowa * HH + lq * 8;
    v4f acc = vz;
#pragma unroll
    for (int ks = 0; ks < 4; ++ks)
      acc = MFMA(ld8(ap + ks * 32), bf[ks], acc);
#pragma unroll
    for (int r = 0; r < 4; ++r) {
      int row = w * 256 + mt * 16 + lq * 4 + r;
      g_emb[row * OUTN + col] = f2bf(acc[r] + bias);
    }
  }
}

// ---- epilogue: out = emb @ dec_w + dec_b, transposed MFMA -> 16B coalesced stores ----
__global__ __launch_bounds__(256) void kdec(const float* __restrict__ decb, float* __restrict__ out) {
  const int tid = threadIdx.x, wv = tid >> 6, l = tid & 63;
  const int lm = l & 15, lq = l >> 4;
  const int c0 = blockIdx.x * 16;         // grid 600
  const int R0 = wv * 256;
  v8s af[8];
#pragma unroll
  for (int ks = 0; ks < 8; ++ks) af[ks] = ld8(&g_decwt[(size_t)(c0 + lm) * OUTN + ks * 32 + lq * 8]);
  float bias[4];
#pragma unroll
  for (int r = 0; r < 4; ++r) bias[r] = decb[c0 + lq * 4 + r];
  const v4f vz = {0.f, 0.f, 0.f, 0.f};
#pragma unroll
  for (int mt = 0; mt < 16; ++mt) {
    const int row = R0 + mt * 16 + lm;
    const ush* bp = g_emb + (size_t)row * OUTN + lq * 8;
    v4f acc = vz;
#pragma unroll
    for (int ks = 0; ks < 8; ++ks)
      acc = MFMA(af[ks], ld8(bp + ks * 32), acc);
    v4f o;
#pragma unroll
    for (int r = 0; r < 4; ++r) o[r] = acc[r] + bias[r];
    *reinterpret_cast<v4f*>(&out[(size_t)row * DECN + c0 + lq * 4]) = o;
  }
}

extern "C" void kernel_launch(void* const* d_in, const int* in_sizes, int n_in,
                              void* d_out, int out_size, void* d_ws, size_t ws_size,
                              hipStream_t stream) {
  const float* seq  = (const float*)d_in[0];
  const float* Wih0 = (const float*)d_in[1];
  const float* Whh0 = (const float*)d_in[2];
  const float* b0   = (const float*)d_in[3];
  const float* gih0 = (const float*)d_in[4];
  const float* bih0 = (const float*)d_in[5];
  const float* ghh0 = (const float*)d_in[6];
  const float* bhh0 = (const float*)d_in[7];
  const float* gc0  = (const float*)d_in[8];
  const float* bc0  = (const float*)d_in[9];
  const float* Wih1 = (const float*)d_in[10];
  const float* Whh1 = (const float*)d_in[11];
  const float* b1   = (const float*)d_in[12];
  const float* gih1 = (const float*)d_in[13];
  const float* bih1 = (const float*)d_in[14];
  const float* ghh1 = (const float*)d_in[15];
  const float* bhh1 = (const float*)d_in[16];
  const float* gc1  = (const float*)d_in[17];
  const float* bc1  = (const float*)d_in[18];
  const float* fcw  = (const float*)d_in[19];
  const float* fcb  = (const float*)d_in[20];
  const float* decw = (const float*)d_in[21];
  const float* decb = (const float*)d_in[22];
  float* out = (float*)d_out;
  (void)in_sizes; (void)n_in; (void)out_size; (void)d_ws; (void)ws_size;

  kpackx<<<dim3((TT * BB * KXP) / 256), dim3(256), 0, stream>>>(seq);
  kpackw<<<dim3(10688), dim3(256), 0, stream>>>(Wih0, Whh0, Wih1, Whh1, fcw, decw);
  kprep<<<dim3(TT * 8), dim3(512), 0, stream>>>(gih0, bih0, b0);
  krec4<<<dim3(64), dim3(512), 0, stream>>>(ghh0, bhh0, gc0, bc0,
                                            gih1, bih1, ghh1, bhh1, b1, gc1, bc1);
  kfc<<<dim3(16), dim3(256), 0, stream>>>(fcb);
  kdec<<<dim3(600), dim3(256), 0, stream>>>(decb, out);
}

// Round 6
// 3572.046 us; speedup vs baseline: 5.1830x; 1.1218x over previous
//
#include <hip/hip_runtime.h>
#include <stdint.h>
#include <stddef.h>

#define TT   128
#define BB   1024
#define INN  75
#define HH   128
#define KXP  96
#define OUTN 256
#define DECN 9600
#define EPSB 1e-5f
#define NRB  16          // row-blocks per mesh
#define RWS  64          // rows per block

typedef short v8s __attribute__((ext_vector_type(8)));   // 8 bf16 (4 VGPR) MFMA frag
typedef float v4f __attribute__((ext_vector_type(4)));   // 4 fp32 acc frag
typedef unsigned short ush;
typedef unsigned int   u32;
typedef unsigned long long u64;

#define MFMA(A,B,C) __builtin_amdgcn_mfma_f32_16x16x32_bf16((A),(B),(C),0,0,0)

// ---- static device workspace (fully rewritten every launch) ----
__device__ __align__(256) ush g_xpad[(size_t)TT * BB * KXP];   // x padded to K=96, [t][b][k] bf16
__device__ __align__(256) u64 g_G1[(size_t)TT * 32 * BB * 4];  // BN(x@Wih0)+b0, [t][g][row][16 bf16]
// weights [m][k] bf16, m permuted: origcol(m) = (m&3)*128 + (m>>4)*4 + ((m>>2)&3)
__device__ __align__(256) ush g_wtih0[512 * KXP];
__device__ __align__(256) ush g_wthh0[512 * HH];
__device__ __align__(256) ush g_wtih1[512 * HH];
__device__ __align__(256) ush g_wthh1[512 * HH];
__device__ __align__(256) ush g_fcwt[OUTN * HH];               // fc_w^T [col][k]
__device__ __align__(256) ush g_decwt[(size_t)DECN * OUTN];    // dec_w^T [col][k]
__device__ __align__(256) ush g_emb[BB * OUTN];                // fc output bf16
__device__ __align__(256) u64 g_hfin[BB * 32];                 // h1[TT-1], 4 bf16/u64 (for kfc)

// ---- tagged cross-block streams: u64 = [gen:32 | payload:32], t-indexed,
// single-writer, never reused within a launch. Relaxed agent atomics only.
__device__ __align__(256) u64 g_th0[(size_t)TT * BB * 64];     // h0: [t][row][64] (2 bf16/word)
__device__ __align__(256) u64 g_th1[(size_t)TT * BB * 64];     // h1
__device__ __align__(256) u64 g_gp[(size_t)TT * 4 * NRB * 1024]; // gate partials [t][mesh][rb][st*512+m*2+ro]
__device__ __align__(256) u64 g_cp[(size_t)TT * 4 * NRB * 128];  // c partials [t][mesh][rb][u*2+ro]
__device__ u32 g_ep[64];                                       // per-block epoch (+=TT per launch)

// ---- helpers ----
__device__ __forceinline__ ush f2bf(float f) {
  u32 u = __float_as_uint(f);
  u32 r = (u + 0x7FFFu + ((u >> 16) & 1u)) >> 16;   // RNE
  return (ush)r;
}
__device__ __forceinline__ float bf2f(ush u) { return __uint_as_float(((u32)u) << 16); }
__device__ __forceinline__ float sigf(float x)  { return 1.f / (1.f + __expf(-x)); }
__device__ __forceinline__ float tanhf_(float x){ float e = __expf(2.f * x); return 1.f - 2.f / (e + 1.f); }
__device__ __forceinline__ v8s ld8(const ush* p) { return *reinterpret_cast<const v8s*>(p); }
__device__ __forceinline__ int origcol(int m) { return (m & 3) * 128 + (m >> 4) * 4 + ((m >> 2) & 3); }

__device__ __forceinline__ u64 ald(const u64* p) {
  return __hip_atomic_load(p, __ATOMIC_RELAXED, __HIP_MEMORY_SCOPE_AGENT);
}
__device__ __forceinline__ void ast(u64* p, u64 v) {
  __hip_atomic_store(p, v, __ATOMIC_RELAXED, __HIP_MEMORY_SCOPE_AGENT);
}
// XOR-swizzled byte offset into a [64 rows][256 B] LDS h-tile (2-way max conflicts)
__device__ __forceinline__ int hswz(int r, int b) { return (r * 256 + b) ^ ((r & 7) << 4); }
__device__ __forceinline__ v8s ld8l(const char* lds, int r, int b) {
  return *reinterpret_cast<const v8s*>(lds + hswz(r, b));
}

// ---- prep kernels (unchanged, verified) ----
__global__ void kpackx(const float* __restrict__ seq) {
  int idx = blockIdx.x * 256 + threadIdx.x;   // < TT*BB*KXP
  int kk = idx % KXP; int rest = idx / KXP;
  int b = rest % BB;  int t = rest / BB;
  float v = (kk < INN) ? seq[((size_t)b * TT + t) * INN + kk] : 0.f;
  g_xpad[idx] = f2bf(v);
}

__global__ void kpackw(const float* __restrict__ Wih0, const float* __restrict__ Whh0,
                       const float* __restrict__ Wih1, const float* __restrict__ Whh1,
                       const float* __restrict__ fcw,  const float* __restrict__ decw) {
  int idx = blockIdx.x * 256 + threadIdx.x;   // grid 10688
  if (idx < 49152) {                          // wtih0: [m][96]
    int m = idx / KXP, k = idx % KXP;
    g_wtih0[idx] = f2bf((k < INN) ? Wih0[k * 512 + origcol(m)] : 0.f);
  } else if (idx < 114688) {
    int j = idx - 49152; int m = j / HH, k = j % HH;
    g_wthh0[j] = f2bf(Whh0[k * 512 + origcol(m)]);
  } else if (idx < 180224) {
    int j = idx - 114688; int m = j / HH, k = j % HH;
    g_wtih1[j] = f2bf(Wih1[k * 512 + origcol(m)]);
  } else if (idx < 245760) {
    int j = idx - 180224; int m = j / HH, k = j % HH;
    g_wthh1[j] = f2bf(Whh1[k * 512 + origcol(m)]);
  } else if (idx < 278528) {                  // fcwt [c][128]
    int j = idx - 245760; int c = j / HH, k = j % HH;
    g_fcwt[j] = f2bf(fcw[k * OUTN + c]);
  } else {                                    // decwt [c][256], coalesced reads
    int j = idx - 278528; int n = j % DECN, k = j / DECN;
    g_decwt[(size_t)n * OUTN + k] = f2bf(decw[(size_t)k * DECN + n]);
  }
}

// G1[t][g][row][16] = BN_ih0(x_t @ Wih0) + b0 (folded), transposed-MFMA orientation.
__global__ __launch_bounds__(512) void kprep(const float* __restrict__ gih0,
                                             const float* __restrict__ bih0,
                                             const float* __restrict__ b0) {
  const int t = blockIdx.x >> 3, ct = blockIdx.x & 7;
  const int tid = threadIdx.x, wv = tid >> 6, l = tid & 63;
  const int lm = l & 15, lq = l >> 4;
  const int R0 = wv * 128;
  __shared__ float sred[8][64][2];
  __shared__ float scoef[64][2];

  v8s af[4][3];
#pragma unroll
  for (int tt = 0; tt < 4; ++tt)
#pragma unroll
    for (int ks = 0; ks < 3; ++ks)
      af[tt][ks] = ld8(&g_wtih0[(ct * 64 + tt * 16 + lm) * KXP + ks * 32 + lq * 8]);

  const v4f vz = {0.f, 0.f, 0.f, 0.f};
  v4f acc[8][4];
#pragma unroll
  for (int mt = 0; mt < 8; ++mt)
#pragma unroll
    for (int tt = 0; tt < 4; ++tt) acc[mt][tt] = vz;

#pragma unroll
  for (int mt = 0; mt < 8; ++mt) {
    const ush* xr = g_xpad + ((size_t)t * BB + R0 + mt * 16 + lm) * KXP + lq * 8;
    v8s bx0 = ld8(xr), bx1 = ld8(xr + 32), bx2 = ld8(xr + 64);
#pragma unroll
    for (int tt = 0; tt < 4; ++tt) {
      acc[mt][tt] = MFMA(af[tt][0], bx0, acc[mt][tt]);
      acc[mt][tt] = MFMA(af[tt][1], bx1, acc[mt][tt]);
      acc[mt][tt] = MFMA(af[tt][2], bx2, acc[mt][tt]);
    }
  }
  float S[4][4], Q[4][4];
#pragma unroll
  for (int tt = 0; tt < 4; ++tt)
#pragma unroll
    for (int r = 0; r < 4; ++r) {
      float s = 0.f, q = 0.f;
#pragma unroll
      for (int mt = 0; mt < 8; ++mt) { float a = acc[mt][tt][r]; s += a; q += a * a; }
#pragma unroll
      for (int off = 1; off < 16; off <<= 1) { s += __shfl_xor(s, off); q += __shfl_xor(q, off); }
      S[tt][r] = s; Q[tt][r] = q;
    }
  if (lm == 0)
#pragma unroll
    for (int tt = 0; tt < 4; ++tt)
#pragma unroll
      for (int r = 0; r < 4; ++r) {
        sred[wv][tt * 16 + lq * 4 + r][0] = S[tt][r];
        sred[wv][tt * 16 + lq * 4 + r][1] = Q[tt][r];
      }
  __syncthreads();
  if (tid < 64) {
    float Sa = 0.f, Qa = 0.f;
#pragma unroll
    for (int w8 = 0; w8 < 8; ++w8) { Sa += sred[w8][tid][0]; Qa += sred[w8][tid][1]; }
    int oc = origcol(ct * 64 + tid);
    float m_ = Sa * (1.f / BB), v_ = Qa * (1.f / BB) - m_ * m_;
    float A = gih0[oc] * rsqrtf(v_ + EPSB);
    scoef[tid][0] = A; scoef[tid][1] = bih0[oc] - A * m_ + b0[oc];
  }
  __syncthreads();
  float CA[4][4], CD[4][4];
#pragma unroll
  for (int tt = 0; tt < 4; ++tt)
#pragma unroll
    for (int r = 0; r < 4; ++r) {
      CA[tt][r] = scoef[tt * 16 + lq * 4 + r][0];
      CD[tt][r] = scoef[tt * 16 + lq * 4 + r][1];
    }
#pragma unroll
  for (int mt = 0; mt < 8; ++mt) {
    const int row = R0 + mt * 16 + lm;
#pragma unroll
    for (int tt = 0; tt < 4; ++tt) {
      const int g = ct * 4 + tt;
      u32 lo = (u32)f2bf(CA[tt][0] * acc[mt][tt][0] + CD[tt][0])
             | ((u32)f2bf(CA[tt][1] * acc[mt][tt][1] + CD[tt][1]) << 16);
      u32 hi = (u32)f2bf(CA[tt][2] * acc[mt][tt][2] + CD[tt][2])
             | ((u32)f2bf(CA[tt][3] * acc[mt][tt][3] + CD[tt][3]) << 16);
      g_G1[(((size_t)t * 32 + g) * BB + row) * 4 + lq] = (u64)lo | ((u64)hi << 32);
    }
  }
}

// ---- krec6: row-owner recurrence, flag-free tagged-word sync (zero fences).
// 64 blocks x 512 thr. Block = (L=bid>>5, H=(bid>>4)&1, rb=bid&15):
// rows [rb*64,+64) x m-cols [H*256,+256). Every cross-block u64 carries its
// generation tag in the high 32 bits; consumers equality-poll. All streams
// t-indexed single-writer (no reuse -> race-free); relaxed agent atomics are
// coherent without fences. h tiles staged in XOR-swizzled LDS: own half
// written locally each step, sibling half polled (16 KB).
__global__ __launch_bounds__(512, 1) void krec6(
    const float* __restrict__ ghh0, const float* __restrict__ bhh0,
    const float* __restrict__ gc0,  const float* __restrict__ bc0,
    const float* __restrict__ gih1, const float* __restrict__ bih1,
    const float* __restrict__ ghh1, const float* __restrict__ bhh1,
    const float* __restrict__ b1,   const float* __restrict__ gc1,
    const float* __restrict__ bc1) {
  const int bid = blockIdx.x;            // 0..63
  const int L = bid >> 5, H = (bid >> 4) & 1, rb = bid & 15;
  const int mesh = L * 2 + H;
  const int tid = threadIdx.x, w = tid >> 6, l = tid & 63;
  const int lm = l & 15, lq = l >> 4;
  const int R0 = rb * RWS;

  __shared__ u64 s_hA_[2048];            // h tile A: L0 h0[t-1]; L1 h0[t]  (16 KB)
  __shared__ u64 s_hB_[2048];            // h tile B: L1 h1[t-1]
  __shared__ float s_gA[256], s_gB[256], s_bs[256];
  __shared__ float s_cgM[64], s_cbM[64];
  __shared__ float s_cA[256], s_cB[256], s_cD[256], s_mual[2][256];
  __shared__ float s_ccA[64], s_ccD[64];
  __shared__ u32 s_base;
  char* const hA = reinterpret_cast<char*>(s_hA_);
  char* const hB = reinterpret_cast<char*>(s_hB_);

  if (tid == 0)
    s_base = __hip_atomic_load(&g_ep[bid], __ATOMIC_RELAXED, __HIP_MEMORY_SCOPE_AGENT);
  if (tid < 256) {
    const int oc = origcol(H * 256 + tid);
    if (L == 0) { s_gA[tid] = ghh0[oc]; s_gB[tid] = 0.f; s_bs[tid] = bhh0[oc]; }
    else { s_gA[tid] = gih1[oc]; s_gB[tid] = ghh1[oc];
           s_bs[tid] = bih1[oc] + bhh1[oc] + b1[oc]; }
  }
  if (tid < 64) {
    const int u = H * 64 + tid;
    s_cgM[tid] = (L ? gc1 : gc0)[u];
    s_cbM[tid] = (L ? bc1 : bc0)[u];
  }
  __syncthreads();
  const u32 base = s_base;

  // persistent weight fragments: wave w owns colTiles ct=0,1 -> cols H*256+(w*2+ct)*16..+15
  v8s afA[2][4], afB[2][4];
  {
    const ush* wA = L ? g_wtih1 : g_wthh0;
#pragma unroll
    for (int ct = 0; ct < 2; ++ct)
#pragma unroll
      for (int ks = 0; ks < 4; ++ks) {
        const int mrow = H * 256 + (w * 2 + ct) * 16 + lm;
        afA[ct][ks] = ld8(&wA[mrow * HH + ks * 32 + lq * 8]);
        if (L) afB[ct][ks] = ld8(&g_wthh1[mrow * HH + ks * 32 + lq * 8]);
      }
  }

  float creg[4][2] = {{0.f,0.f},{0.f,0.f},{0.f,0.f},{0.f,0.f}};
  float so_[4][2];
  const v4f vz = {0.f, 0.f, 0.f, 0.f};

#pragma unroll 1
  for (int t = 0; t < TT; ++t) {
    const u32 tagP = base + (u32)t;        // tag of step t-1 products
    const u32 tagC = base + (u32)t + 1;    // tag of step t products
    v4f PA[4][2], PB[4][2];
#pragma unroll
    for (int mt = 0; mt < 4; ++mt) {
      PA[mt][0] = vz; PA[mt][1] = vz; PB[mt][0] = vz; PB[mt][1] = vz;
    }
    u64 g1v[4][2];

    if (L == 0) {     // G1 prefetch (plain cached loads; launch-constant data)
#pragma unroll
      for (int mt = 0; mt < 4; ++mt)
#pragma unroll
        for (int ct = 0; ct < 2; ++ct)
          g1v[mt][ct] = g_G1[(((size_t)t * 32 + H * 16 + w * 2 + ct) * BB
                              + R0 + mt * 16 + lm) * 4 + lq];
    }

    // ---- phase G: poll + stage h tiles into LDS ----
    if (L == 0) {
      if (t > 0) {     // sibling half of own h0[t-1] (own half already in LDS)
        const int row = tid >> 3, j0 = (tid & 7) * 4;
        const u64* p = g_th0 + ((size_t)(t - 1) * BB + R0 + row) * 64 + (1 - H) * 32 + j0;
        u64 v[4];
#pragma unroll
        for (int k = 0; k < 4; ++k) v[k] = ald(p + k);
        for (;;) {
          bool ok = true;
#pragma unroll
          for (int k = 0; k < 4; ++k)
            if ((u32)(v[k] >> 32) != tagP) { v[k] = ald(p + k); ok = false; }
          if (ok) break;
          __builtin_amdgcn_s_sleep(1);
        }
#pragma unroll
        for (int k = 0; k < 4; ++k)
          *reinterpret_cast<u32*>(hA + hswz(row, ((1 - H) * 32 + j0 + k) * 4)) = (u32)v[k];
      }
    } else {
      {                // full h0[t]
        const int row = tid >> 3, j0 = (tid & 7) * 8;
        const u64* p = g_th0 + ((size_t)t * BB + R0 + row) * 64 + j0;
        u64 v[8];
#pragma unroll
        for (int k = 0; k < 8; ++k) v[k] = ald(p + k);
        for (;;) {
          bool ok = true;
#pragma unroll
          for (int k = 0; k < 8; ++k)
            if ((u32)(v[k] >> 32) != tagC) { v[k] = ald(p + k); ok = false; }
          if (ok) break;
          __builtin_amdgcn_s_sleep(1);
        }
#pragma unroll
        for (int k = 0; k < 8; ++k)
          *reinterpret_cast<u32*>(hA + hswz(row, (j0 + k) * 4)) = (u32)v[k];
      }
      if (t > 0) {     // sibling half of own h1[t-1]
        const int row = tid >> 3, j0 = (tid & 7) * 4;
        const u64* p = g_th1 + ((size_t)(t - 1) * BB + R0 + row) * 64 + (1 - H) * 32 + j0;
        u64 v[4];
#pragma unroll
        for (int k = 0; k < 4; ++k) v[k] = ald(p + k);
        for (;;) {
          bool ok = true;
#pragma unroll
          for (int k = 0; k < 4; ++k)
            if ((u32)(v[k] >> 32) != tagP) { v[k] = ald(p + k); ok = false; }
          if (ok) break;
          __builtin_amdgcn_s_sleep(1);
        }
#pragma unroll
        for (int k = 0; k < 4; ++k)
          *reinterpret_cast<u32*>(hB + hswz(row, ((1 - H) * 32 + j0 + k) * 4)) = (u32)v[k];
      }
    }
    __syncthreads();

    // ---- GEMMs from LDS ----
    if (L == 0) {
      if (t > 0) {
#pragma unroll
        for (int mt = 0; mt < 4; ++mt)
#pragma unroll
          for (int ks = 0; ks < 4; ++ks) {
            const v8s f = ld8l(hA, mt * 16 + lm, ks * 64 + lq * 16);
            PA[mt][0] = MFMA(afA[0][ks], f, PA[mt][0]);
            PA[mt][1] = MFMA(afA[1][ks], f, PA[mt][1]);
          }
      }
    } else {
#pragma unroll
      for (int mt = 0; mt < 4; ++mt)
#pragma unroll
        for (int ks = 0; ks < 4; ++ks) {
          const v8s f = ld8l(hA, mt * 16 + lm, ks * 64 + lq * 16);
          PA[mt][0] = MFMA(afA[0][ks], f, PA[mt][0]);
          PA[mt][1] = MFMA(afA[1][ks], f, PA[mt][1]);
        }
      if (t > 0) {
#pragma unroll
        for (int mt = 0; mt < 4; ++mt)
#pragma unroll
          for (int ks = 0; ks < 4; ++ks) {
            const v8s f = ld8l(hB, mt * 16 + lm, ks * 64 + lq * 16);
            PB[mt][0] = MFMA(afB[0][ks], f, PB[mt][0]);
            PB[mt][1] = MFMA(afB[1][ks], f, PB[mt][1]);
          }
      }
    }

    // ---- phase S: gate stats over own 64 rows -> tagged publish ----
    u64* const gpO = g_gp + (((size_t)t * 4 + mesh) * NRB + rb) * 1024;
#pragma unroll
    for (int ct = 0; ct < 2; ++ct) {
      float sA[4], qA[4], sB[4], qB[4];
#pragma unroll
      for (int r = 0; r < 4; ++r) {
        float s1 = PA[0][ct][r] + PA[1][ct][r] + PA[2][ct][r] + PA[3][ct][r];
        float q1 = PA[0][ct][r]*PA[0][ct][r] + PA[1][ct][r]*PA[1][ct][r]
                 + PA[2][ct][r]*PA[2][ct][r] + PA[3][ct][r]*PA[3][ct][r];
        float s2 = PB[0][ct][r] + PB[1][ct][r] + PB[2][ct][r] + PB[3][ct][r];
        float q2 = PB[0][ct][r]*PB[0][ct][r] + PB[1][ct][r]*PB[1][ct][r]
                 + PB[2][ct][r]*PB[2][ct][r] + PB[3][ct][r]*PB[3][ct][r];
#pragma unroll
        for (int off = 1; off < 16; off <<= 1) {
          s1 += __shfl_xor(s1, off); q1 += __shfl_xor(q1, off);
          if (L) { s2 += __shfl_xor(s2, off); q2 += __shfl_xor(q2, off); }
        }
        sA[r] = s1; qA[r] = q1; sB[r] = s2; qB[r] = q2;
      }
      if (lm == 0) {
        const int m0 = (w * 2 + ct) * 16 + lq * 4;
        const u64 tg = ((u64)tagC) << 32;
#pragma unroll
        for (int r = 0; r < 4; ++r) {
          ast(&gpO[(m0 + r) * 2],     tg | __float_as_uint(sA[r]));
          ast(&gpO[(m0 + r) * 2 + 1], tg | __float_as_uint(qA[r]));
          if (L) {
            ast(&gpO[512 + (m0 + r) * 2],     tg | __float_as_uint(sB[r]));
            ast(&gpO[512 + (m0 + r) * 2 + 1], tg | __float_as_uint(qB[r]));
          }
        }
      }
    }
    __syncthreads();   // publishes issued before any poll (deadlock safety)

    // ---- phase C: poll 16 rb partials, reduce, coefs ----
    {
      const int st = tid >> 8, m = tid & 255;
      if (st == 0 || L == 1) {
        float S = 0.f, Q = 0.f;
#pragma unroll
        for (int half = 0; half < 2; ++half) {
          u64 vv[16];
#pragma unroll
          for (int r2 = 0; r2 < 8; ++r2) {
            const u64* p = g_gp + (((size_t)t * 4 + mesh) * NRB + half * 8 + r2) * 1024
                         + st * 512 + m * 2;
            vv[2 * r2] = ald(p); vv[2 * r2 + 1] = ald(p + 1);
          }
          for (;;) {
            bool ok = true;
#pragma unroll
            for (int r2 = 0; r2 < 8; ++r2) {
              const u64* p = g_gp + (((size_t)t * 4 + mesh) * NRB + half * 8 + r2) * 1024
                           + st * 512 + m * 2;
              if ((u32)(vv[2 * r2] >> 32) != tagC)     { vv[2 * r2] = ald(p);     ok = false; }
              if ((u32)(vv[2 * r2 + 1] >> 32) != tagC) { vv[2 * r2 + 1] = ald(p + 1); ok = false; }
            }
            if (ok) break;
            __builtin_amdgcn_s_sleep(1);
          }
#pragma unroll
          for (int r2 = 0; r2 < 8; ++r2) {
            S += __uint_as_float((u32)vv[2 * r2]);
            Q += __uint_as_float((u32)vv[2 * r2 + 1]);
          }
        }
        const float mu = S * (1.f / BB), var = Q * (1.f / BB) - mu * mu;
        const float A = (st ? s_gB[m] : s_gA[m]) * rsqrtf(var + EPSB);
        if (st == 0) s_cA[m] = A; else s_cB[m] = A;
        s_mual[st][m] = A * mu;
      }
    }
    __syncthreads();
    if (tid < 256) s_cD[tid] = s_bs[tid] - s_mual[0][tid] - (L ? s_mual[1][tid] : 0.f);
    __syncthreads();

    // ---- pointwise + c update + c-stat publish ----
    u64* const cpO = g_cp + (((size_t)t * 4 + mesh) * NRB + rb) * 128;
#pragma unroll
    for (int ct = 0; ct < 2; ++ct) {
      const int mb = (w * 2 + ct) * 16 + lq * 4;
      const v4f cA = *reinterpret_cast<const v4f*>(&s_cA[mb]);
      const v4f cD = *reinterpret_cast<const v4f*>(&s_cD[mb]);
      const v4f cB = *reinterpret_cast<const v4f*>(&s_cB[mb]);
      float cs = 0.f, cq = 0.f;
#pragma unroll
      for (int mt = 0; mt < 4; ++mt) {
        float gv[4];
        if (L == 0) {
          const u64 g1 = g1v[mt][ct];
          gv[0] = bf2f((ush)g1)         + cA[0] * PA[mt][ct][0] + cD[0];
          gv[1] = bf2f((ush)(g1 >> 16)) + cA[1] * PA[mt][ct][1] + cD[1];
          gv[2] = bf2f((ush)(g1 >> 32)) + cA[2] * PA[mt][ct][2] + cD[2];
          gv[3] = bf2f((ush)(g1 >> 48)) + cA[3] * PA[mt][ct][3] + cD[3];
        } else {
#pragma unroll
          for (int r = 0; r < 4; ++r)
            gv[r] = cA[r] * PA[mt][ct][r] + cB[r] * PB[mt][ct][r] + cD[r];
        }
        const float cold = (t == 0) ? 0.f : creg[mt][ct];
        const float c1 = sigf(gv[0]) * cold + sigf(gv[1]) * tanhf_(gv[3]);
        creg[mt][ct] = c1; so_[mt][ct] = sigf(gv[2]);
        cs += c1; cq += c1 * c1;
      }
#pragma unroll
      for (int off = 1; off < 16; off <<= 1) { cs += __shfl_xor(cs, off); cq += __shfl_xor(cq, off); }
      if (lm == 0) {
        const int u = (w * 2 + ct) * 4 + lq;
        const u64 tg = ((u64)tagC) << 32;
        ast(&cpO[u * 2],     tg | __float_as_uint(cs));
        ast(&cpO[u * 2 + 1], tg | __float_as_uint(cq));
      }
    }
    __syncthreads();   // publishes issued before polls

    // ---- phase C2: c-BN reduce + coefs ----
    if (tid < 64) {
      float S = 0.f, Q = 0.f;
#pragma unroll
      for (int half = 0; half < 2; ++half) {
        u64 vv[16];
#pragma unroll
        for (int r2 = 0; r2 < 8; ++r2) {
          const u64* p = g_cp + (((size_t)t * 4 + mesh) * NRB + half * 8 + r2) * 128 + tid * 2;
          vv[2 * r2] = ald(p); vv[2 * r2 + 1] = ald(p + 1);
        }
        for (;;) {
          bool ok = true;
#pragma unroll
          for (int r2 = 0; r2 < 8; ++r2) {
            const u64* p = g_cp + (((size_t)t * 4 + mesh) * NRB + half * 8 + r2) * 128 + tid * 2;
            if ((u32)(vv[2 * r2] >> 32) != tagC)     { vv[2 * r2] = ald(p);     ok = false; }
            if ((u32)(vv[2 * r2 + 1] >> 32) != tagC) { vv[2 * r2 + 1] = ald(p + 1); ok = false; }
          }
          if (ok) break;
          __builtin_amdgcn_s_sleep(1);
        }
#pragma unroll
        for (int r2 = 0; r2 < 8; ++r2) {
          S += __uint_as_float((u32)vv[2 * r2]);
          Q += __uint_as_float((u32)vv[2 * r2 + 1]);
        }
      }
      const float mu = S * (1.f / BB), var = Q * (1.f / BB) - mu * mu;
      const float ac = s_cgM[tid] * rsqrtf(var + EPSB);
      s_ccA[tid] = ac; s_ccD[tid] = s_cbM[tid] - ac * mu;
    }
    __syncthreads();

    // ---- phase H: h compute -> LDS own-half + tagged global publish ----
    u64* const th = (L ? g_th1 : g_th0) + ((size_t)t * BB + R0) * 64;
    char* const lown = L ? hB : hA;
#pragma unroll
    for (int ct = 0; ct < 2; ++ct) {
      const int ul = (w * 2 + ct) * 4 + lq;
      const float ac = s_ccA[ul], dc = s_ccD[ul];
#pragma unroll
      for (int mt = 0; mt < 4; ++mt) {
        const int rowl = mt * 16 + lm;
        const u32 v = (u32)f2bf(so_[mt][ct] * tanhf_(ac * creg[mt][ct] + dc));
        const u32 a = v | (__shfl_xor(v, 16) << 16);   // valid on even lq
        if (lq == 0 || lq == 2) {
          const int jg = H * 32 + (w * 2 + ct) * 2 + (lq >> 1);
          *reinterpret_cast<u32*>(lown + hswz(rowl, jg * 4)) = a;
          ast(&th[(size_t)rowl * 64 + jg], (((u64)tagC) << 32) | a);
        }
        const u32 b2 = __shfl_xor(a, 32);
        if (L == 1 && t == TT - 1 && lq == 0)
          g_hfin[(size_t)(R0 + rowl) * 32 + H * 16 + (w * 2 + ct)] = (u64)a | ((u64)b2 << 32);
      }
    }
    __syncthreads();   // H stores issued + LDS tile complete before next step
  }

  if (tid == 0)
    __hip_atomic_store(&g_ep[bid], base + TT, __ATOMIC_RELAXED, __HIP_MEMORY_SCOPE_AGENT);
}

// ---- epilogue: emb = h1(T-1) @ fc_w + fc_b (bf16 out) ----
__global__ __launch_bounds__(256) void kfc(const float* __restrict__ fcb) {
  const int tid = threadIdx.x, w = tid >> 6, l = tid & 63;
  const int lm = l & 15, lq = l >> 4;
  const int col = blockIdx.x * 16 + lm;   // grid 16
  const ush* hsrc = reinterpret_cast<const ush*>(g_hfin);
  v8s bf[4];
#pragma unroll
  for (int ks = 0; ks < 4; ++ks) bf[ks] = ld8(&g_fcwt[col * HH + ks * 32 + lq * 8]);
  const float bias = fcb[col];
  const v4f vz = {0.f, 0.f, 0.f, 0.f};
#pragma unroll
  for (int mt = 0; mt < 16; ++mt) {
    const int rowa = w * 256 + mt * 16 + lm;
    const ush* ap = hsrc + (size_t)rowa * HH + lq * 8;
    v4f acc = vz;
#pragma unroll
    for (int ks = 0; ks < 4; ++ks)
      acc = MFMA(ld8(ap + ks * 32), bf[ks], acc);
#pragma unroll
    for (int r = 0; r < 4; ++r) {
      int row = w * 256 + mt * 16 + lq * 4 + r;
      g_emb[row * OUTN + col] = f2bf(acc[r] + bias);
    }
  }
}

// ---- epilogue: out = emb @ dec_w + dec_b, transposed MFMA -> 16B coalesced stores ----
__global__ __launch_bounds__(256) void kdec(const float* __restrict__ decb, float* __restrict__ out) {
  const int tid = threadIdx.x, wv = tid >> 6, l = tid & 63;
  const int lm = l & 15, lq = l >> 4;
  const int c0 = blockIdx.x * 16;         // grid 600
  const int R0 = wv * 256;
  v8s af[8];
#pragma unroll
  for (int ks = 0; ks < 8; ++ks) af[ks] = ld8(&g_decwt[(size_t)(c0 + lm) * OUTN + ks * 32 + lq * 8]);
  float bias[4];
#pragma unroll
  for (int r = 0; r < 4; ++r) bias[r] = decb[c0 + lq * 4 + r];
  const v4f vz = {0.f, 0.f, 0.f, 0.f};
#pragma unroll
  for (int mt = 0; mt < 16; ++mt) {
    const int row = R0 + mt * 16 + lm;
    const ush* bp = g_emb + (size_t)row * OUTN + lq * 8;
    v4f acc = vz;
#pragma unroll
    for (int ks = 0; ks < 8; ++ks)
      acc = MFMA(af[ks], ld8(bp + ks * 32), acc);
    v4f o;
#pragma unroll
    for (int r = 0; r < 4; ++r) o[r] = acc[r] + bias[r];
    *reinterpret_cast<v4f*>(&out[(size_t)row * DECN + c0 + lq * 4]) = o;
  }
}

extern "C" void kernel_launch(void* const* d_in, const int* in_sizes, int n_in,
                              void* d_out, int out_size, void* d_ws, size_t ws_size,
                              hipStream_t stream) {
  const float* seq  = (const float*)d_in[0];
  const float* Wih0 = (const float*)d_in[1];
  const float* Whh0 = (const float*)d_in[2];
  const float* b0   = (const float*)d_in[3];
  const float* gih0 = (const float*)d_in[4];
  const float* bih0 = (const float*)d_in[5];
  const float* ghh0 = (const float*)d_in[6];
  const float* bhh0 = (const float*)d_in[7];
  const float* gc0  = (const float*)d_in[8];
  const float* bc0  = (const float*)d_in[9];
  const float* Wih1 = (const float*)d_in[10];
  const float* Whh1 = (const float*)d_in[11];
  const float* b1   = (const float*)d_in[12];
  const float* gih1 = (const float*)d_in[13];
  const float* bih1 = (const float*)d_in[14];
  const float* ghh1 = (const float*)d_in[15];
  const float* bhh1 = (const float*)d_in[16];
  const float* gc1  = (const float*)d_in[17];
  const float* bc1  = (const float*)d_in[18];
  const float* fcw  = (const float*)d_in[19];
  const float* fcb  = (const float*)d_in[20];
  const float* decw = (const float*)d_in[21];
  const float* decb = (const float*)d_in[22];
  float* out = (float*)d_out;
  (void)in_sizes; (void)n_in; (void)out_size; (void)d_ws; (void)ws_size;

  kpackx<<<dim3((TT * BB * KXP) / 256), dim3(256), 0, stream>>>(seq);
  kpackw<<<dim3(10688), dim3(256), 0, stream>>>(Wih0, Whh0, Wih1, Whh1, fcw, decw);
  kprep<<<dim3(TT * 8), dim3(512), 0, stream>>>(gih0, bih0, b0);
  krec6<<<dim3(64), dim3(512), 0, stream>>>(ghh0, bhh0, gc0, bc0,
                                            gih1, bih1, ghh1, bhh1, b1, gc1, bc1);
  kfc<<<dim3(16), dim3(256), 0, stream>>>(fcb);
  kdec<<<dim3(600), dim3(256), 0, stream>>>(decb, out);
}

// Round 7
// 3037.601 us; speedup vs baseline: 6.0949x; 1.1759x over previous
//
#include <hip/hip_runtime.h>
#include <stdint.h>
#include <stddef.h>

#define TT   128
#define BB   1024
#define INN  75
#define HH   128
#define KXP  96
#define OUTN 256
#define DECN 9600
#define EPSB 1e-5f
#define NRB  16          // row-blocks per mesh
#define RWS  64          // rows per block

typedef short v8s __attribute__((ext_vector_type(8)));   // 8 bf16 (4 VGPR) MFMA frag
typedef float v4f __attribute__((ext_vector_type(4)));   // 4 fp32 acc frag
typedef unsigned short ush;
typedef unsigned int   u32;
typedef unsigned long long u64;

#define MFMA(A,B,C) __builtin_amdgcn_mfma_f32_16x16x32_bf16((A),(B),(C),0,0,0)

// ---- static device workspace (fully rewritten every launch) ----
__device__ __align__(256) ush g_xpad[(size_t)TT * BB * KXP];   // x padded to K=96, [t][b][k] bf16
__device__ __align__(256) u64 g_G1[(size_t)TT * 32 * BB * 4];  // BN(x@Wih0)+b0, [t][g][row][16 bf16]
// weights [m][k] bf16, m permuted: origcol(m) = (m&3)*128 + (m>>4)*4 + ((m>>2)&3)
__device__ __align__(256) ush g_wtih0[512 * KXP];
__device__ __align__(256) ush g_wthh0[512 * HH];
__device__ __align__(256) ush g_wtih1[512 * HH];
__device__ __align__(256) ush g_wthh1[512 * HH];
__device__ __align__(256) ush g_fcwt[OUTN * HH];               // fc_w^T [col][k]
__device__ __align__(256) ush g_decwt[(size_t)DECN * OUTN];    // dec_w^T [col][k]
__device__ __align__(256) ush g_emb[BB * OUTN];                // fc output bf16
__device__ __align__(256) u64 g_hfin[BB * 32];                 // h1[TT-1], 4 bf16/u64 (for kfc)

// ---- tagged cross-block streams. t-indexed, single-writer, never reused
// within a launch. Relaxed agent atomics only; tag+payload share one u64.
// u64 formats: th0: [gen32 | 2 bf16]; gp/cp/soc: [tag16 | a:f24 | b:f24]
// (tag16 safe: stale data is exactly 1 launch = 128 generations old; 128 != 0 mod 2^16)
__device__ __align__(256) u64 g_th0[(size_t)TT * BB * 64];          // h0: [t][row][64]
__device__ __align__(256) u64 g_gp[(size_t)2 * TT * 2 * NRB * 512]; // [L][t][H][rb][col256][st2] (S,Q)
__device__ __align__(256) u64 g_cp[(size_t)2 * TT * 2 * NRB * 64];  // [L][t][H][rb][ul] (S,Q of c)
__device__ __align__(256) u64 g_soc[(size_t)2 * TT * 2 * BB * 64];  // [L][t][H][row][ul] (so,c)
__device__ u32 g_ep[64];                                            // per-block epoch (+=TT/launch)

// ---- helpers ----
__device__ __forceinline__ ush f2bf(float f) {
  u32 u = __float_as_uint(f);
  u32 r = (u + 0x7FFFu + ((u >> 16) & 1u)) >> 16;   // RNE
  return (ush)r;
}
__device__ __forceinline__ float bf2f(ush u) { return __uint_as_float(((u32)u) << 16); }
__device__ __forceinline__ float sigf(float x)  { return 1.f / (1.f + __expf(-x)); }
__device__ __forceinline__ float tanhf_(float x){ float e = __expf(2.f * x); return 1.f - 2.f / (e + 1.f); }
__device__ __forceinline__ v8s ld8(const ush* p) { return *reinterpret_cast<const v8s*>(p); }
__device__ __forceinline__ int origcol(int m) { return (m & 3) * 128 + (m >> 4) * 4 + ((m >> 2) & 3); }

__device__ __forceinline__ u64 ald(const u64* p) {
  return __hip_atomic_load(p, __ATOMIC_RELAXED, __HIP_MEMORY_SCOPE_AGENT);
}
__device__ __forceinline__ void ast(u64* p, u64 v) {
  __hip_atomic_store(p, v, __ATOMIC_RELAXED, __HIP_MEMORY_SCOPE_AGENT);
}
__device__ __forceinline__ u64 pk24(u32 tag, float a, float b) {
  return ((u64)(tag & 0xFFFFu) << 48)
       | ((u64)(__float_as_uint(a) >> 8) << 24)
       | (u64)(__float_as_uint(b) >> 8);
}
__device__ __forceinline__ float upA24(u64 w) { return __uint_as_float(((u32)(w >> 24) & 0xFFFFFFu) << 8); }
__device__ __forceinline__ float upB24(u64 w) { return __uint_as_float(((u32)w & 0xFFFFFFu) << 8); }
__device__ __forceinline__ u32 tg16(u64 w) { return (u32)(w >> 48); }
// XOR-swizzled byte offset into a [64 rows][256 B] LDS h-tile
__device__ __forceinline__ int hswz(int r, int b) { return (r * 256 + b) ^ ((r & 7) << 4); }
__device__ __forceinline__ v8s ld8l(const char* lds, int r, int b) {
  return *reinterpret_cast<const v8s*>(lds + hswz(r, b));
}

// ---- prep kernels (unchanged, verified) ----
__global__ void kpackx(const float* __restrict__ seq) {
  int idx = blockIdx.x * 256 + threadIdx.x;   // < TT*BB*KXP
  int kk = idx % KXP; int rest = idx / KXP;
  int b = rest % BB;  int t = rest / BB;
  float v = (kk < INN) ? seq[((size_t)b * TT + t) * INN + kk] : 0.f;
  g_xpad[idx] = f2bf(v);
}

__global__ void kpackw(const float* __restrict__ Wih0, const float* __restrict__ Whh0,
                       const float* __restrict__ Wih1, const float* __restrict__ Whh1,
                       const float* __restrict__ fcw,  const float* __restrict__ decw) {
  int idx = blockIdx.x * 256 + threadIdx.x;   // grid 10688
  if (idx < 49152) {                          // wtih0: [m][96]
    int m = idx / KXP, k = idx % KXP;
    g_wtih0[idx] = f2bf((k < INN) ? Wih0[k * 512 + origcol(m)] : 0.f);
  } else if (idx < 114688) {
    int j = idx - 49152; int m = j / HH, k = j % HH;
    g_wthh0[j] = f2bf(Whh0[k * 512 + origcol(m)]);
  } else if (idx < 180224) {
    int j = idx - 114688; int m = j / HH, k = j % HH;
    g_wtih1[j] = f2bf(Wih1[k * 512 + origcol(m)]);
  } else if (idx < 245760) {
    int j = idx - 180224; int m = j / HH, k = j % HH;
    g_wthh1[j] = f2bf(Whh1[k * 512 + origcol(m)]);
  } else if (idx < 278528) {                  // fcwt [c][128]
    int j = idx - 245760; int c = j / HH, k = j % HH;
    g_fcwt[j] = f2bf(fcw[k * OUTN + c]);
  } else {                                    // decwt [c][256], coalesced reads
    int j = idx - 278528; int n = j % DECN, k = j / DECN;
    g_decwt[(size_t)n * OUTN + k] = f2bf(decw[(size_t)k * DECN + n]);
  }
}

// G1[t][g][row][16] = BN_ih0(x_t @ Wih0) + b0 (folded), transposed-MFMA orientation.
__global__ __launch_bounds__(512) void kprep(const float* __restrict__ gih0,
                                             const float* __restrict__ bih0,
                                             const float* __restrict__ b0) {
  const int t = blockIdx.x >> 3, ct = blockIdx.x & 7;
  const int tid = threadIdx.x, wv = tid >> 6, l = tid & 63;
  const int lm = l & 15, lq = l >> 4;
  const int R0 = wv * 128;
  __shared__ float sred[8][64][2];
  __shared__ float scoef[64][2];

  v8s af[4][3];
#pragma unroll
  for (int tt = 0; tt < 4; ++tt)
#pragma unroll
    for (int ks = 0; ks < 3; ++ks)
      af[tt][ks] = ld8(&g_wtih0[(ct * 64 + tt * 16 + lm) * KXP + ks * 32 + lq * 8]);

  const v4f vz = {0.f, 0.f, 0.f, 0.f};
  v4f acc[8][4];
#pragma unroll
  for (int mt = 0; mt < 8; ++mt)
#pragma unroll
    for (int tt = 0; tt < 4; ++tt) acc[mt][tt] = vz;

#pragma unroll
  for (int mt = 0; mt < 8; ++mt) {
    const ush* xr = g_xpad + ((size_t)t * BB + R0 + mt * 16 + lm) * KXP + lq * 8;
    v8s bx0 = ld8(xr), bx1 = ld8(xr + 32), bx2 = ld8(xr + 64);
#pragma unroll
    for (int tt = 0; tt < 4; ++tt) {
      acc[mt][tt] = MFMA(af[tt][0], bx0, acc[mt][tt]);
      acc[mt][tt] = MFMA(af[tt][1], bx1, acc[mt][tt]);
      acc[mt][tt] = MFMA(af[tt][2], bx2, acc[mt][tt]);
    }
  }
  float S[4][4], Q[4][4];
#pragma unroll
  for (int tt = 0; tt < 4; ++tt)
#pragma unroll
    for (int r = 0; r < 4; ++r) {
      float s = 0.f, q = 0.f;
#pragma unroll
      for (int mt = 0; mt < 8; ++mt) { float a = acc[mt][tt][r]; s += a; q += a * a; }
#pragma unroll
      for (int off = 1; off < 16; off <<= 1) { s += __shfl_xor(s, off); q += __shfl_xor(q, off); }
      S[tt][r] = s; Q[tt][r] = q;
    }
  if (lm == 0)
#pragma unroll
    for (int tt = 0; tt < 4; ++tt)
#pragma unroll
      for (int r = 0; r < 4; ++r) {
        sred[wv][tt * 16 + lq * 4 + r][0] = S[tt][r];
        sred[wv][tt * 16 + lq * 4 + r][1] = Q[tt][r];
      }
  __syncthreads();
  if (tid < 64) {
    float Sa = 0.f, Qa = 0.f;
#pragma unroll
    for (int w8 = 0; w8 < 8; ++w8) { Sa += sred[w8][tid][0]; Qa += sred[w8][tid][1]; }
    int oc = origcol(ct * 64 + tid);
    float m_ = Sa * (1.f / BB), v_ = Qa * (1.f / BB) - m_ * m_;
    float A = gih0[oc] * rsqrtf(v_ + EPSB);
    scoef[tid][0] = A; scoef[tid][1] = bih0[oc] - A * m_ + b0[oc];
  }
  __syncthreads();
  float CA[4][4], CD[4][4];
#pragma unroll
  for (int tt = 0; tt < 4; ++tt)
#pragma unroll
    for (int r = 0; r < 4; ++r) {
      CA[tt][r] = scoef[tt * 16 + lq * 4 + r][0];
      CD[tt][r] = scoef[tt * 16 + lq * 4 + r][1];
    }
#pragma unroll
  for (int mt = 0; mt < 8; ++mt) {
    const int row = R0 + mt * 16 + lm;
#pragma unroll
    for (int tt = 0; tt < 4; ++tt) {
      const int g = ct * 4 + tt;
      u32 lo = (u32)f2bf(CA[tt][0] * acc[mt][tt][0] + CD[tt][0])
             | ((u32)f2bf(CA[tt][1] * acc[mt][tt][1] + CD[tt][1]) << 16);
      u32 hi = (u32)f2bf(CA[tt][2] * acc[mt][tt][2] + CD[tt][2])
             | ((u32)f2bf(CA[tt][3] * acc[mt][tt][3] + CD[tt][3]) << 16);
      g_G1[(((size_t)t * 32 + g) * BB + row) * 4 + lq] = (u64)lo | ((u64)hi << 32);
    }
  }
}

// ---- krec7: R6 geometry, 2 tagged rounds/step (gate + c), (so,c) exchange.
// 64 blocks x 512 thr. Block = (L=bid>>5, H=(bid>>4)&1, rb=bid&15):
// rows [rb*64,+64) x m-cols [H*256,+256). h never crosses blocks as its own
// round: blocks publish (so,c) f24-packed WITH the c-partials; after the
// c-round every block rebuilds its sibling's h-half locally (bit-identical:
// both sides compute from the same f24 so,c). L1 reads the h0 stream (L0
// free-runs ahead -> poll hits ready data). All cross-block words are
// [tag|payload] single u64s, relaxed agent atomics, zero fences.
__global__ __launch_bounds__(512, 1) void krec7(
    const float* __restrict__ ghh0, const float* __restrict__ bhh0,
    const float* __restrict__ gc0,  const float* __restrict__ bc0,
    const float* __restrict__ gih1, const float* __restrict__ bih1,
    const float* __restrict__ ghh1, const float* __restrict__ bhh1,
    const float* __restrict__ b1,   const float* __restrict__ gc1,
    const float* __restrict__ bc1) {
  const int bid = blockIdx.x;            // 0..63
  const int L = bid >> 5, H = (bid >> 4) & 1, rb = bid & 15;
  const int tid = threadIdx.x, w = tid >> 6, l = tid & 63;
  const int lm = l & 15, lq = l >> 4;
  const int R0 = rb * RWS;

  __shared__ u64 s_hA_[2048];            // L0: h0 recurrent tile; L1: staged h0[t]
  __shared__ u64 s_hB_[2048];            // L1: h1 recurrent tile
  __shared__ float s_gA[256], s_gB[256], s_bs[256];
  __shared__ float s_cgM[128], s_cbM[128];       // ALL 128 units of the layer
  __shared__ float s_cA[256], s_cB[256], s_cD[256], s_mual[2][256];
  __shared__ float s_ccA[128], s_ccD[128];
  __shared__ u32 s_base;
  char* const hA = reinterpret_cast<char*>(s_hA_);
  char* const hB = reinterpret_cast<char*>(s_hB_);

  if (tid == 0)
    s_base = __hip_atomic_load(&g_ep[bid], __ATOMIC_RELAXED, __HIP_MEMORY_SCOPE_AGENT);
  if (tid < 256) {
    const int oc = origcol(H * 256 + tid);
    if (L == 0) { s_gA[tid] = ghh0[oc]; s_gB[tid] = 0.f; s_bs[tid] = bhh0[oc]; }
    else { s_gA[tid] = gih1[oc]; s_gB[tid] = ghh1[oc];
           s_bs[tid] = bih1[oc] + bhh1[oc] + b1[oc]; }
  }
  if (tid < 128) {
    s_cgM[tid] = (L ? gc1 : gc0)[tid];
    s_cbM[tid] = (L ? bc1 : bc0)[tid];
  }
  __syncthreads();
  const u32 base = s_base;

  // persistent weight fragments: wave w owns colTiles ct=0,1 -> cols H*256+(w*2+ct)*16..+15
  v8s afA[2][4], afB[2][4];
  {
    const ush* wA = L ? g_wtih1 : g_wthh0;
#pragma unroll
    for (int ct = 0; ct < 2; ++ct)
#pragma unroll
      for (int ks = 0; ks < 4; ++ks) {
        const int mrow = H * 256 + (w * 2 + ct) * 16 + lm;
        afA[ct][ks] = ld8(&wA[mrow * HH + ks * 32 + lq * 8]);
        if (L) afB[ct][ks] = ld8(&g_wthh1[mrow * HH + ks * 32 + lq * 8]);
      }
  }

  float creg[4][2] = {{0.f,0.f},{0.f,0.f},{0.f,0.f},{0.f,0.f}};
  const v4f vz = {0.f, 0.f, 0.f, 0.f};

#pragma unroll 1
  for (int t = 0; t < TT; ++t) {
    const u32 tagF = base + (u32)t + 1;
    const u32 t16 = tagF & 0xFFFFu;
    v4f PA[4][2], PB[4][2];
#pragma unroll
    for (int mt = 0; mt < 4; ++mt) {
      PA[mt][0] = vz; PA[mt][1] = vz; PB[mt][0] = vz; PB[mt][1] = vz;
    }
    u64 g1v[4][2];

    if (L == 0) {     // G1 prefetch (plain cached loads; launch-constant data)
#pragma unroll
      for (int mt = 0; mt < 4; ++mt)
#pragma unroll
        for (int ct = 0; ct < 2; ++ct)
          g1v[mt][ct] = g_G1[(((size_t)t * 32 + H * 16 + w * 2 + ct) * BB
                              + R0 + mt * 16 + lm) * 4 + lq];
    } else {
      // stage hA = h0[t] from tagged stream (L0 runs ahead -> usually ready)
      const int row = tid >> 3, j0 = (tid & 7) * 8;
      const u64* p = g_th0 + ((size_t)t * BB + R0 + row) * 64 + j0;
      u64 v[8];
#pragma unroll
      for (int k = 0; k < 8; ++k) v[k] = ald(p + k);
      for (;;) {
        bool ok = true;
#pragma unroll
        for (int k = 0; k < 8; ++k)
          if ((u32)(v[k] >> 32) != tagF) { v[k] = ald(p + k); ok = false; }
        if (ok) break;
        __builtin_amdgcn_s_sleep(1);
      }
#pragma unroll
      for (int k = 0; k < 8; ++k)
        *reinterpret_cast<u32*>(hA + hswz(row, (j0 + k) * 4)) = (u32)v[k];
    }
    __syncthreads();

    // ---- GEMMs from LDS (no polls on the recurrent path) ----
    if (L == 0) {
      if (t > 0) {
#pragma unroll
        for (int mt = 0; mt < 4; ++mt)
#pragma unroll
          for (int ks = 0; ks < 4; ++ks) {
            const v8s f = ld8l(hA, mt * 16 + lm, ks * 64 + lq * 16);
            PA[mt][0] = MFMA(afA[0][ks], f, PA[mt][0]);
            PA[mt][1] = MFMA(afA[1][ks], f, PA[mt][1]);
          }
      }
    } else {
#pragma unroll
      for (int mt = 0; mt < 4; ++mt)
#pragma unroll
        for (int ks = 0; ks < 4; ++ks) {
          const v8s f = ld8l(hA, mt * 16 + lm, ks * 64 + lq * 16);
          PA[mt][0] = MFMA(afA[0][ks], f, PA[mt][0]);
          PA[mt][1] = MFMA(afA[1][ks], f, PA[mt][1]);
        }
      if (t > 0) {
#pragma unroll
        for (int mt = 0; mt < 4; ++mt)
#pragma unroll
          for (int ks = 0; ks < 4; ++ks) {
            const v8s f = ld8l(hB, mt * 16 + lm, ks * 64 + lq * 16);
            PB[mt][0] = MFMA(afB[0][ks], f, PB[mt][0]);
            PB[mt][1] = MFMA(afB[1][ks], f, PB[mt][1]);
          }
      }
    }

    // ---- gate stats over own 64 rows -> packed tagged publish (1 word/col/stream) ----
    u64* const gpO = g_gp + ((((size_t)L * TT + t) * 2 + H) * NRB + rb) * 512;
#pragma unroll
    for (int ct = 0; ct < 2; ++ct) {
      float sA[4], qA[4], sB[4], qB[4];
#pragma unroll
      for (int r = 0; r < 4; ++r) {
        float s1 = PA[0][ct][r] + PA[1][ct][r] + PA[2][ct][r] + PA[3][ct][r];
        float q1 = PA[0][ct][r]*PA[0][ct][r] + PA[1][ct][r]*PA[1][ct][r]
                 + PA[2][ct][r]*PA[2][ct][r] + PA[3][ct][r]*PA[3][ct][r];
        float s2 = PB[0][ct][r] + PB[1][ct][r] + PB[2][ct][r] + PB[3][ct][r];
        float q2 = PB[0][ct][r]*PB[0][ct][r] + PB[1][ct][r]*PB[1][ct][r]
                 + PB[2][ct][r]*PB[2][ct][r] + PB[3][ct][r]*PB[3][ct][r];
#pragma unroll
        for (int off = 1; off < 16; off <<= 1) {
          s1 += __shfl_xor(s1, off); q1 += __shfl_xor(q1, off);
          if (L) { s2 += __shfl_xor(s2, off); q2 += __shfl_xor(q2, off); }
        }
        sA[r] = s1; qA[r] = q1; sB[r] = s2; qB[r] = q2;
      }
      if (lm == 0) {
        const int m0 = (w * 2 + ct) * 16 + lq * 4;
#pragma unroll
        for (int r = 0; r < 4; ++r) {
          ast(&gpO[(m0 + r) * 2], pk24(tagF, sA[r], qA[r]));
          if (L) ast(&gpO[(m0 + r) * 2 + 1], pk24(tagF, sB[r], qB[r]));
        }
      }
    }
    __syncthreads();

    // ---- ROUND 1: gate all-to-all poll + coefs ----
    {
      const int st = tid >> 8, m = tid & 255;
      if (st == 0 || L == 1) {
        const u64* pb = g_gp + (((size_t)L * TT + t) * 2 + H) * NRB * 512 + m * 2 + st;
        u64 v[16];
#pragma unroll
        for (int r2 = 0; r2 < 16; ++r2) v[r2] = ald(pb + (size_t)r2 * 512);
        for (;;) {
          bool ok = true;
#pragma unroll
          for (int r2 = 0; r2 < 16; ++r2)
            if (tg16(v[r2]) != t16) { v[r2] = ald(pb + (size_t)r2 * 512); ok = false; }
          if (ok) break;
          __builtin_amdgcn_s_sleep(1);
        }
        float S = 0.f, Q = 0.f;
#pragma unroll
        for (int r2 = 0; r2 < 16; ++r2) { S += upA24(v[r2]); Q += upB24(v[r2]); }
        const float mu = S * (1.f / BB), var = Q * (1.f / BB) - mu * mu;
        const float A = (st ? s_gB[m] : s_gA[m]) * rsqrtf(var + EPSB);
        if (st == 0) s_cA[m] = A; else s_cB[m] = A;
        s_mual[st][m] = A * mu;
      }
    }
    __syncthreads();
    if (tid < 256) s_cD[tid] = s_bs[tid] - s_mual[0][tid] - (L ? s_mual[1][tid] : 0.f);
    __syncthreads();

    // ---- pointwise + c update; publish (so,c) f24 AND c-partials together ----
    u64* const cpO = g_cp + ((((size_t)L * TT + t) * 2 + H) * NRB + rb) * 64;
    u64* const socO = g_soc + (((size_t)L * TT + t) * 2 + H) * BB * 64;
    float soq[4][2], cq_[4][2];
#pragma unroll
    for (int ct = 0; ct < 2; ++ct) {
      const int mb = (w * 2 + ct) * 16 + lq * 4;
      const v4f cA = *reinterpret_cast<const v4f*>(&s_cA[mb]);
      const v4f cD = *reinterpret_cast<const v4f*>(&s_cD[mb]);
      const v4f cB = *reinterpret_cast<const v4f*>(&s_cB[mb]);
      const int ul = (w * 2 + ct) * 4 + lq;
      float cs = 0.f, cqs = 0.f;
#pragma unroll
      for (int mt = 0; mt < 4; ++mt) {
        float gv[4];
        if (L == 0) {
          const u64 g1 = g1v[mt][ct];
          gv[0] = bf2f((ush)g1)         + cA[0] * PA[mt][ct][0] + cD[0];
          gv[1] = bf2f((ush)(g1 >> 16)) + cA[1] * PA[mt][ct][1] + cD[1];
          gv[2] = bf2f((ush)(g1 >> 32)) + cA[2] * PA[mt][ct][2] + cD[2];
          gv[3] = bf2f((ush)(g1 >> 48)) + cA[3] * PA[mt][ct][3] + cD[3];
        } else {
#pragma unroll
          for (int r = 0; r < 4; ++r)
            gv[r] = cA[r] * PA[mt][ct][r] + cB[r] * PB[mt][ct][r] + cD[r];
        }
        const float cold = (t == 0) ? 0.f : creg[mt][ct];
        const float c1 = sigf(gv[0]) * cold + sigf(gv[1]) * tanhf_(gv[3]);
        creg[mt][ct] = c1;
        const float so = sigf(gv[2]);
        const u64 ws = pk24(tagF, so, c1);
        ast(&socO[(size_t)(R0 + mt * 16 + lm) * 64 + ul], ws);
        const float soQ = upA24(ws), cQ = upB24(ws);   // quantized copies (bit-shared w/ sibling)
        soq[mt][ct] = soQ; cq_[mt][ct] = cQ;
        cs += cQ; cqs += cQ * cQ;
      }
#pragma unroll
      for (int off = 1; off < 16; off <<= 1) { cs += __shfl_xor(cs, off); cqs += __shfl_xor(cqs, off); }
      if (lm == 0) ast(&cpO[ul], pk24(tagF, cs, cqs));
    }
    __syncthreads();

    // ---- ROUND 2: c-partials (tid<128, unit tid, 16 sources) + sibling (so,c) ----
    u64 sv[8];
    if (tid < 128) {
      const int Hs = tid >> 6, us = tid & 63;
      const u64* pc = g_cp + (((size_t)L * TT + t) * 2 + Hs) * NRB * 64 + us;
      u64 v[16];
#pragma unroll
      for (int r2 = 0; r2 < 16; ++r2) v[r2] = ald(pc + (size_t)r2 * 64);
      for (;;) {
        bool ok = true;
#pragma unroll
        for (int r2 = 0; r2 < 16; ++r2)
          if (tg16(v[r2]) != t16) { v[r2] = ald(pc + (size_t)r2 * 64); ok = false; }
        if (ok) break;
        __builtin_amdgcn_s_sleep(1);
      }
      float S = 0.f, Q = 0.f;
#pragma unroll
      for (int r2 = 0; r2 < 16; ++r2) { S += upA24(v[r2]); Q += upB24(v[r2]); }
      const float mu = S * (1.f / BB), var = Q * (1.f / BB) - mu * mu;
      const float ac = s_cgM[tid] * rsqrtf(var + EPSB);
      s_ccA[tid] = ac; s_ccD[tid] = s_cbM[tid] - ac * mu;
    }
    {
      const int rloc = tid >> 3, u0 = (tid & 7) * 8;
      const u64* ps = g_soc + (((size_t)L * TT + t) * 2 + (1 - H)) * BB * 64
                    + (size_t)(R0 + rloc) * 64 + u0;
#pragma unroll
      for (int k = 0; k < 8; ++k) sv[k] = ald(ps + k);
      for (;;) {
        bool ok = true;
#pragma unroll
        for (int k = 0; k < 8; ++k)
          if (tg16(sv[k]) != t16) { sv[k] = ald(ps + k); ok = false; }
        if (ok) break;
        __builtin_amdgcn_s_sleep(1);
      }
    }
    __syncthreads();

    // ---- h: own half (regs) + sibling half (from sv) -> LDS; L0 publishes th0 ----
    char* const town = L ? hB : hA;
#pragma unroll
    for (int ct = 0; ct < 2; ++ct) {
      const int ul = (w * 2 + ct) * 4 + lq;
      const int ug = H * 64 + ul;
      const float ac = s_ccA[ug], dc = s_ccD[ug];
#pragma unroll
      for (int mt = 0; mt < 4; ++mt) {
        const int rowl = mt * 16 + lm;
        const u32 v = (u32)f2bf(soq[mt][ct] * tanhf_(ac * cq_[mt][ct] + dc));
        const u32 a = v | (__shfl_xor(v, 16) << 16);   // valid on even lq
        if (lq == 0 || lq == 2) {
          const int jg = H * 32 + (w * 2 + ct) * 2 + (lq >> 1);
          *reinterpret_cast<u32*>(town + hswz(rowl, jg * 4)) = a;
          if (L == 0)
            ast(&g_th0[((size_t)t * BB + R0 + rowl) * 64 + jg], (((u64)tagF) << 32) | a);
        }
        if (L == 1 && t == TT - 1) {
          const u32 b2 = __shfl_xor(a, 32);
          if (lq == 0)
            g_hfin[(size_t)(R0 + rowl) * 32 + H * 16 + (w * 2 + ct)] = (u64)a | ((u64)b2 << 32);
        }
      }
    }
    {
      const int rloc = tid >> 3, u0 = (tid & 7) * 8;
#pragma unroll
      for (int k = 0; k < 8; ++k) {
        const int ugs = (1 - H) * 64 + u0 + k;
        const float hs = upA24(sv[k]) * tanhf_(s_ccA[ugs] * upB24(sv[k]) + s_ccD[ugs]);
        *reinterpret_cast<ush*>(town + hswz(rloc, ugs * 2)) = f2bf(hs);
      }
    }
    __syncthreads();   // tiles complete + publishes issued before next step
  }

  if (tid == 0)
    __hip_atomic_store(&g_ep[bid], base + TT, __ATOMIC_RELAXED, __HIP_MEMORY_SCOPE_AGENT);
}

// ---- epilogue: emb = h1(T-1) @ fc_w + fc_b (bf16 out) ----
__global__ __launch_bounds__(256) void kfc(const float* __restrict__ fcb) {
  const int tid = threadIdx.x, w = tid >> 6, l = tid & 63;
  const int lm = l & 15, lq = l >> 4;
  const int col = blockIdx.x * 16 + lm;   // grid 16
  const ush* hsrc = reinterpret_cast<const ush*>(g_hfin);
  v8s bf[4];
#pragma unroll
  for (int ks = 0; ks < 4; ++ks) bf[ks] = ld8(&g_fcwt[col * HH + ks * 32 + lq * 8]);
  const float bias = fcb[col];
  const v4f vz = {0.f, 0.f, 0.f, 0.f};
#pragma unroll
  for (int mt = 0; mt < 16; ++mt) {
    const int rowa = w * 256 + mt * 16 + lm;
    const ush* ap = hsrc + (size_t)rowa * HH + lq * 8;
    v4f acc = vz;
#pragma unroll
    for (int ks = 0; ks < 4; ++ks)
      acc = MFMA(ld8(ap + ks * 32), bf[ks], acc);
#pragma unroll
    for (int r = 0; r < 4; ++r) {
      int row = w * 256 + mt * 16 + lq * 4 + r;
      g_emb[row * OUTN + col] = f2bf(acc[r] + bias);
    }
  }
}

// ---- epilogue: out = emb @ dec_w + dec_b, transposed MFMA -> 16B coalesced stores ----
__global__ __launch_bounds__(256) void kdec(const float* __restrict__ decb, float* __restrict__ out) {
  const int tid = threadIdx.x, wv = tid >> 6, l = tid & 63;
  const int lm = l & 15, lq = l >> 4;
  const int c0 = blockIdx.x * 16;         // grid 600
  const int R0 = wv * 256;
  v8s af[8];
#pragma unroll
  for (int ks = 0; ks < 8; ++ks) af[ks] = ld8(&g_decwt[(size_t)(c0 + lm) * OUTN + ks * 32 + lq * 8]);
  float bias[4];
#pragma unroll
  for (int r = 0; r < 4; ++r) bias[r] = decb[c0 + lq * 4 + r];
  const v4f vz = {0.f, 0.f, 0.f, 0.f};
#pragma unroll
  for (int mt = 0; mt < 16; ++mt) {
    const int row = R0 + mt * 16 + lm;
    const ush* bp = g_emb + (size_t)row * OUTN + lq * 8;
    v4f acc = vz;
#pragma unroll
    for (int ks = 0; ks < 8; ++ks)
      acc = MFMA(af[ks], ld8(bp + ks * 32), acc);
    v4f o;
#pragma unroll
    for (int r = 0; r < 4; ++r) o[r] = acc[r] + bias[r];
    *reinterpret_cast<v4f*>(&out[(size_t)row * DECN + c0 + lq * 4]) = o;
  }
}

extern "C" void kernel_launch(void* const* d_in, const int* in_sizes, int n_in,
                              void* d_out, int out_size, void* d_ws, size_t ws_size,
                              hipStream_t stream) {
  const float* seq  = (const float*)d_in[0];
  const float* Wih0 = (const float*)d_in[1];
  const float* Whh0 = (const float*)d_in[2];
  const float* b0   = (const float*)d_in[3];
  const float* gih0 = (const float*)d_in[4];
  const float* bih0 = (const float*)d_in[5];
  const float* ghh0 = (const float*)d_in[6];
  const float* bhh0 = (const float*)d_in[7];
  const float* gc0  = (const float*)d_in[8];
  const float* bc0  = (const float*)d_in[9];
  const float* Wih1 = (const float*)d_in[10];
  const float* Whh1 = (const float*)d_in[11];
  const float* b1   = (const float*)d_in[12];
  const float* gih1 = (const float*)d_in[13];
  const float* bih1 = (const float*)d_in[14];
  const float* ghh1 = (const float*)d_in[15];
  const float* bhh1 = (const float*)d_in[16];
  const float* gc1  = (const float*)d_in[17];
  const float* bc1  = (const float*)d_in[18];
  const float* fcw  = (const float*)d_in[19];
  const float* fcb  = (const float*)d_in[20];
  const float* decw = (const float*)d_in[21];
  const float* decb = (const float*)d_in[22];
  float* out = (float*)d_out;
  (void)in_sizes; (void)n_in; (void)out_size; (void)d_ws; (void)ws_size;

  kpackx<<<dim3((TT * BB * KXP) / 256), dim3(256), 0, stream>>>(seq);
  kpackw<<<dim3(10688), dim3(256), 0, stream>>>(Wih0, Whh0, Wih1, Whh1, fcw, decw);
  kprep<<<dim3(TT * 8), dim3(512), 0, stream>>>(gih0, bih0, b0);
  krec7<<<dim3(64), dim3(512), 0, stream>>>(ghh0, bhh0, gc0, bc0,
                                            gih1, bih1, ghh1, bhh1, b1, gc1, bc1);
  kfc<<<dim3(16), dim3(256), 0, stream>>>(fcb);
  kdec<<<dim3(600), dim3(256), 0, stream>>>(decb, out);
}